// Round 1
// baseline (247.392 us; speedup 1.0000x reference)
//
#include <hip/hip_runtime.h>
#include <hip/hip_cooperative_groups.h>
#include <math.h>

namespace cg = cooperative_groups;

constexpr int NB = 1024;   // batch
constexpr int NT = 256;    // topic_size
constexpr int NE = 300;    // embedding_size
constexpr int NBATCH = 2;  // batches per main-phase block

#if defined(__has_builtin)
#if __has_builtin(__builtin_amdgcn_exp2f)
#define EXP2F(x) __builtin_amdgcn_exp2f(x)
#else
#define EXP2F(x) exp2f(x)
#endif
#if __has_builtin(__builtin_amdgcn_logf)
#define LOG2F(x) __builtin_amdgcn_logf(x)
#else
#define LOG2F(x) log2f(x)
#endif
#else
#define EXP2F(x) exp2f(x)
#define LOG2F(x) log2f(x)
#endif

__device__ __forceinline__ float rdlane(float v, int l) {
  return __uint_as_float(__builtin_amdgcn_readlane(__float_as_uint(v), l));
}

// ============================================================================
// Fused cooperative kernel: phase M -> grid.sync -> phase G -> grid.sync ->
// phase main.  512 blocks x 1024 thr, __launch_bounds__(1024,8) => VGPR<=64,
// LDS ~21KB => exactly 2 blocks/CU * 256 CU = 512 co-resident (coop-valid).
// Phases M/G are the proven k_M/k_G bodies on blocks 0..255 (others wait).
// grid.sync() provides the agent-scope release/acquire needed for cross-XCD
// visibility of the d_ws intermediates (incl. cross-iteration staleness).
// ============================================================================
__global__ __launch_bounds__(1024, 8) void k_all(
    const float* __restrict__ req, const float* __restrict__ wsdl,
    const float* __restrict__ TE, const float* __restrict__ wf,
    const float* __restrict__ bf, float* __restrict__ Mt,
    float* __restrict__ Mrow, float* __restrict__ G2, float* __restrict__ u2,
    float* __restrict__ Gd, float* __restrict__ Gof, float* __restrict__ out) {
  __shared__ float RA[4][NT], RB[4][NT], RC[4][NT], RD[4][NT];
  __shared__ float2 L2s[NT];
  __shared__ float2 Q2s[NT];
  __shared__ float finU[16];
  __shared__ float fin[16][6];
  __shared__ float fin2[4][2];

  auto gg = cg::this_grid();
  const float LOG2E = 1.4426950408889634f;

  int tid = threadIdx.x;
  int blk = blockIdx.x;

  // ===== Phase M (blocks 0..255): Mt[blk][t] = sum_e TE[e,t]*wf[blk,e] =====
  if (blk < NT) {
    int q = __builtin_amdgcn_readfirstlane(tid >> 8);
    int c = tid & 255, lane = tid & 63;
    const float* wrow = wf + blk * NE;
    float4 wa = *(const float4*)(wrow + 4 * lane);
    float4 wb = make_float4(0.f, 0.f, 0.f, 0.f);
    if (lane < 11) wb = *(const float4*)(wrow + 256 + 4 * lane);
    float acc = 0.f;
#pragma unroll
    for (int k = 0; k < 16; ++k) {  // chunks q+4k <= 63
      int ec = q + 4 * k;
      float wx = rdlane(wa.x, ec), wy = rdlane(wa.y, ec);
      float wz = rdlane(wa.z, ec), ww = rdlane(wa.w, ec);
      const float* tp = TE + 4 * ec * NT + c;
      acc = fmaf(tp[0], wx, acc);
      acc = fmaf(tp[NT], wy, acc);
      acc = fmaf(tp[2 * NT], wz, acc);
      acc = fmaf(tp[3 * NT], ww, acc);
    }
#pragma unroll
    for (int k = 16; k < 19; ++k) {  // chunks 64..74
      int ec = q + 4 * k;
      if (ec < 75) {  // wave-uniform
        int l = ec - 64;
        float wx = rdlane(wb.x, l), wy = rdlane(wb.y, l);
        float wz = rdlane(wb.z, l), ww = rdlane(wb.w, l);
        const float* tp = TE + 4 * ec * NT + c;
        acc = fmaf(tp[0], wx, acc);
        acc = fmaf(tp[NT], wy, acc);
        acc = fmaf(tp[2 * NT], wz, acc);
        acc = fmaf(tp[3 * NT], ww, acc);
      }
    }
    RA[q][c] = acc;
    __syncthreads();
    if (q == 0) {
      float s = RA[0][c] + RA[1][c] + RA[2][c] + RA[3][c];
      Mt[blk * NT + c] = s;    // coalesced
      Mrow[c * NT + blk] = s;  // scattered, one-time
    }
  }
  gg.sync();

  // ===== Phase G (blocks 0..255): G2=(M M^T)*log2e, Gd, Gof, u2 =====
  if (blk < NT) {
    int q = __builtin_amdgcn_readfirstlane(tid >> 8);
    int c = tid & 255, lane = tid & 63, wid = tid >> 6;
    const float* mrowp = Mrow + blk * NT;
    float4 ma = *(const float4*)(mrowp + 4 * lane);
    float acc = 0.f;
    int c0 = q * 16;
#pragma unroll
    for (int k = 0; k < 16; ++k) {
      int fc = c0 + k;  // SGPR
      float mx = rdlane(ma.x, fc), my = rdlane(ma.y, fc);
      float mz = rdlane(ma.z, fc), mw = rdlane(ma.w, fc);
      const float* tp = Mt + 4 * fc * NT + c;
      acc = fmaf(tp[0], mx, acc);
      acc = fmaf(tp[NT], my, acc);
      acc = fmaf(tp[2 * NT], mz, acc);
      acc = fmaf(tp[3 * NT], mw, acc);
    }
    RA[q][c] = acc;
    __syncthreads();
    if (q == 0) {
      float g = (RA[0][c] + RA[1][c] + RA[2][c] + RA[3][c]) * LOG2E;
      G2[blk * NT + c] = g;
      if (c == blk) Gd[blk] = g;
      float v = (c == blk) ? -3.0e38f : g;
#pragma unroll
      for (int off = 32; off > 0; off >>= 1) v = fmaxf(v, __shfl_down(v, off, 64));
      if (lane == 0) fin2[wid][0] = v;
      float p = mrowp[c] * bf[c];  // coalesced
#pragma unroll
      for (int off = 32; off > 0; off >>= 1) p += __shfl_down(p, off, 64);
      if (lane == 0) fin2[wid][1] = p;
    }
    __syncthreads();
    if (tid == 0) {
      float gof = fmaxf(fmaxf(fin2[0][0], fin2[1][0]), fmaxf(fin2[2][0], fin2[3][0]));
      Gof[blk] = fmaxf(gof, 0.f);
      u2[blk] = (fin2[0][1] + fin2[1][1] + fin2[2][1] + fin2[3][1]) * LOG2E;
    }
  }
  gg.sync();

  // ===== Phase main (all 512 blocks) — proven k_main body verbatim =====
  {
    int q = tid >> 8, c = tid & 255;
    int lane = tid & 63, wid = tid >> 6;
    int b0 = blk * NBATCH, i0 = q * 64;

    float wb0 = wsdl[b0 * NT + c], wb1 = wsdl[(b0 + 1) * NT + c];
    float rc0 = req[b0 * NT + c], rc1 = req[(b0 + 1) * NT + c];
    float uc = u2[c], gd = Gd[c], gof = Gof[c];

    // Lane-distributed vectors over this quad's index range.
    float rv0 = req[b0 * NT + i0 + lane], rv1 = req[(b0 + 1) * NT + i0 + lane];
    float wv0 = wsdl[b0 * NT + i0 + lane], wv1 = wsdl[(b0 + 1) * NT + i0 + lane];
    float uv = u2[i0 + lane];

    // up = max_i max(u_i, 0): the 16 waves' uv registers cover all 256 i.
    {
      float um = fmaxf(uv, 0.f);
#pragma unroll
      for (int off = 32; off > 0; off >>= 1) um = fmaxf(um, __shfl_down(um, off, 64));
      if (lane == 0) finU[wid] = um;
    }
    __syncthreads();
    float up = finU[0];
#pragma unroll
    for (int w = 1; w < 16; ++w) up = fmaxf(up, finU[w]);

    // Safe softmax upper bound per (batch, column c) — proven absmax 0.0:
    float mh0 = fmaxf(rc0 * fmaf(wb0, gd, uc), fmaf(wb0, gof, up));
    float mh1 = fmaxf(rc1 * fmaf(wb1, gd, uc), fmaf(wb1, gof, up));

    // ---- Pass D: column denominators ----
    float d0 = 0.f, d1 = 0.f;
#pragma unroll 8
    for (int ii = 0; ii < 64; ++ii) {
      float g = G2[(i0 + ii) * NT + c];  // coalesced
      float su = rdlane(uv, ii);
      float s0 = rdlane(rv0, ii), s1 = rdlane(rv1, ii);
      d0 += EXP2F(fmaf(s0, fmaf(wb0, g, su), -mh0));
      d1 += EXP2F(fmaf(s1, fmaf(wb1, g, su), -mh1));
    }
    RA[q][c] = d0;
    RB[q][c] = d1;
    __syncthreads();
    if (q == 0) {
      float2 L;
      L.x = mh0 + LOG2F(RA[0][c] + RA[1][c] + RA[2][c] + RA[3][c]);
      L.y = mh1 + LOG2F(RB[0][c] + RB[1][c] + RB[2][c] + RB[3][c]);
      L2s[c] = L;
    }
    __syncthreads();
    float2 Lq = L2s[i0 + lane];
    float Lv0 = Lq.x, Lv1 = Lq.y;

    // ---- Pass S: row-sums of softmaxed att (row i=c), j over quad range ----
    float S0 = 0.f, S1 = 0.f;
#pragma unroll 8
    for (int jj = 0; jj < 64; ++jj) {
      float g = G2[(i0 + jj) * NT + c];  // G[c][j] by symmetry; coalesced
      float w0 = rdlane(wv0, jj), w1 = rdlane(wv1, jj);
      float l0 = rdlane(Lv0, jj), l1 = rdlane(Lv1, jj);
      S0 += EXP2F(fmaf(rc0, fmaf(w0, g, uc), -l0));
      S1 += EXP2F(fmaf(rc1, fmaf(w1, g, uc), -l1));
    }
    RA[q][c] = S0;
    RB[q][c] = S1;
    __syncthreads();
    if (q == 0) {
      float2 qv;
      qv.x = (RA[0][c] + RA[1][c] + RA[2][c] + RA[3][c]) * rc0;
      qv.y = (RB[0][c] + RB[1][c] + RB[2][c] + RB[3][c]) * rc1;
      Q2s[c] = qv;
    }
    __syncthreads();
    float2 Qq = Q2s[i0 + lane];
    float Qv0 = Qq.x, Qv1 = Qq.y;

    // ---- Pass B: ave_req = (r/T)@M + bf, ave_wsdl = (qv/T)@M + bf ----
    float a0 = 0.f, a1 = 0.f, y0 = 0.f, y1 = 0.f;
#pragma unroll 8
    for (int tt = 0; tt < 64; ++tt) {
      float mk = Mrow[(i0 + tt) * NT + c];  // coalesced
      float s0 = rdlane(rv0, tt), s1 = rdlane(rv1, tt);
      float p0 = rdlane(Qv0, tt), p1 = rdlane(Qv1, tt);
      a0 = fmaf(s0, mk, a0);
      a1 = fmaf(s1, mk, a1);
      y0 = fmaf(p0, mk, y0);
      y1 = fmaf(p1, mk, y1);
    }
    RA[q][c] = a0;
    RB[q][c] = a1;
    RC[q][c] = y0;
    RD[q][c] = y1;
    __syncthreads();
    float st[6];
    {
      float bfc = bf[c];
      const float invT = 1.0f / NT;
      float avr0 = fmaf(RA[0][c] + RA[1][c] + RA[2][c] + RA[3][c], invT, bfc);
      float avr1 = fmaf(RB[0][c] + RB[1][c] + RB[2][c] + RB[3][c], invT, bfc);
      float avw0 = fmaf(RC[0][c] + RC[1][c] + RC[2][c] + RC[3][c], invT, bfc);
      float avw1 = fmaf(RD[0][c] + RD[1][c] + RD[2][c] + RD[3][c], invT, bfc);
      st[0] = avr0 * avw0; st[1] = avr0 * avr0; st[2] = avw0 * avw0;
      st[3] = avr1 * avw1; st[4] = avr1 * avr1; st[5] = avw1 * avw1;
    }
    // 4x quad replication of each c cancels in the final ratio.
#pragma unroll
    for (int k = 0; k < 6; ++k)
#pragma unroll
      for (int off = 32; off > 0; off >>= 1) st[k] += __shfl_down(st[k], off, 64);
    if (lane == 0)
#pragma unroll
      for (int k = 0; k < 6; ++k) fin[wid][k] = st[k];
    __syncthreads();
    if (tid < NBATCH) {
      int bb = tid;
      float N = 0.f, A = 0.f, C = 0.f;
      for (int w = 0; w < 16; ++w) {
        N += fin[w][3 * bb + 0];
        A += fin[w][3 * bb + 1];
        C += fin[w][3 * bb + 2];
      }
      out[b0 + bb] = N / fmaxf(sqrtf(A) * sqrtf(C), 1e-8f) * 3.0f;
    }
  }
}

// ============================================================================
// Fallback path: the proven 3-kernel pipeline (used only if cooperative
// launch is rejected by the runtime — keeps the round safe).
// ============================================================================
__global__ __launch_bounds__(1024) void k_M(const float* __restrict__ TE,
                                            const float* __restrict__ wf,
                                            float* __restrict__ Mt,
                                            float* __restrict__ Mrow) {
  __shared__ float red[4][NT];
  int tid = threadIdx.x;
  int q = __builtin_amdgcn_readfirstlane(tid >> 8);
  int c = tid & 255, lane = tid & 63, blk = blockIdx.x;

  const float* wrow = wf + blk * NE;
  float4 wa = *(const float4*)(wrow + 4 * lane);
  float4 wb = make_float4(0.f, 0.f, 0.f, 0.f);
  if (lane < 11) wb = *(const float4*)(wrow + 256 + 4 * lane);
  float acc = 0.f;
#pragma unroll
  for (int k = 0; k < 16; ++k) {
    int ec = q + 4 * k;
    float wx = rdlane(wa.x, ec), wy = rdlane(wa.y, ec);
    float wz = rdlane(wa.z, ec), ww = rdlane(wa.w, ec);
    const float* tp = TE + 4 * ec * NT + c;
    acc = fmaf(tp[0], wx, acc);
    acc = fmaf(tp[NT], wy, acc);
    acc = fmaf(tp[2 * NT], wz, acc);
    acc = fmaf(tp[3 * NT], ww, acc);
  }
#pragma unroll
  for (int k = 16; k < 19; ++k) {
    int ec = q + 4 * k;
    if (ec < 75) {
      int l = ec - 64;
      float wx = rdlane(wb.x, l), wy = rdlane(wb.y, l);
      float wz = rdlane(wb.z, l), ww = rdlane(wb.w, l);
      const float* tp = TE + 4 * ec * NT + c;
      acc = fmaf(tp[0], wx, acc);
      acc = fmaf(tp[NT], wy, acc);
      acc = fmaf(tp[2 * NT], wz, acc);
      acc = fmaf(tp[3 * NT], ww, acc);
    }
  }
  red[q][c] = acc;
  __syncthreads();
  if (q == 0) {
    float s = red[0][c] + red[1][c] + red[2][c] + red[3][c];
    Mt[blk * NT + c] = s;
    Mrow[c * NT + blk] = s;
  }
}

__global__ __launch_bounds__(1024) void k_G(const float* __restrict__ Mt,
                                            const float* __restrict__ Mrow,
                                            const float* __restrict__ bf,
                                            float* __restrict__ G2,
                                            float* __restrict__ u2,
                                            float* __restrict__ Gd,
                                            float* __restrict__ Gof) {
  __shared__ float red[4][NT];
  __shared__ float fin2[4][2];
  const float LOG2E = 1.4426950408889634f;
  int tid = threadIdx.x;
  int q = __builtin_amdgcn_readfirstlane(tid >> 8);
  int c = tid & 255, lane = tid & 63, wid = tid >> 6, blk = blockIdx.x;

  const float* mrowp = Mrow + blk * NT;
  float4 ma = *(const float4*)(mrowp + 4 * lane);
  float acc = 0.f;
  int c0 = q * 16;
#pragma unroll
  for (int k = 0; k < 16; ++k) {
    int fc = c0 + k;
    float mx = rdlane(ma.x, fc), my = rdlane(ma.y, fc);
    float mz = rdlane(ma.z, fc), mw = rdlane(ma.w, fc);
    const float* tp = Mt + 4 * fc * NT + c;
    acc = fmaf(tp[0], mx, acc);
    acc = fmaf(tp[NT], my, acc);
    acc = fmaf(tp[2 * NT], mz, acc);
    acc = fmaf(tp[3 * NT], mw, acc);
  }
  red[q][c] = acc;
  __syncthreads();
  if (q == 0) {
    float g = (red[0][c] + red[1][c] + red[2][c] + red[3][c]) * LOG2E;
    G2[blk * NT + c] = g;
    if (c == blk) Gd[blk] = g;
    float v = (c == blk) ? -3.0e38f : g;
#pragma unroll
    for (int off = 32; off > 0; off >>= 1) v = fmaxf(v, __shfl_down(v, off, 64));
    if (lane == 0) fin2[wid][0] = v;
    float p = mrowp[c] * bf[c];
#pragma unroll
    for (int off = 32; off > 0; off >>= 1) p += __shfl_down(p, off, 64);
    if (lane == 0) fin2[wid][1] = p;
  }
  __syncthreads();
  if (tid == 0) {
    float gof = fmaxf(fmaxf(fin2[0][0], fin2[1][0]), fmaxf(fin2[2][0], fin2[3][0]));
    Gof[blk] = fmaxf(gof, 0.f);
    u2[blk] = (fin2[0][1] + fin2[1][1] + fin2[2][1] + fin2[3][1]) * LOG2E;
  }
}

__global__ __launch_bounds__(1024, 8) void k_main(
    const float* __restrict__ req, const float* __restrict__ wsdl,
    const float* __restrict__ Mrow, const float* __restrict__ G2,
    const float* __restrict__ u2, const float* __restrict__ Gd,
    const float* __restrict__ Gof, const float* __restrict__ bf,
    float* __restrict__ out) {
  __shared__ float RA[4][NT], RB[4][NT], RC[4][NT], RD[4][NT];
  __shared__ float2 L2s[NT];
  __shared__ float2 Q2s[NT];
  __shared__ float finU[16];
  __shared__ float fin[16][6];

  int tid = threadIdx.x, q = tid >> 8, c = tid & 255;
  int lane = tid & 63, wid = tid >> 6;
  int blk = blockIdx.x, b0 = blk * NBATCH, i0 = q * 64;

  float wb0 = wsdl[b0 * NT + c], wb1 = wsdl[(b0 + 1) * NT + c];
  float rc0 = req[b0 * NT + c], rc1 = req[(b0 + 1) * NT + c];
  float uc = u2[c], gd = Gd[c], gof = Gof[c];

  float rv0 = req[b0 * NT + i0 + lane], rv1 = req[(b0 + 1) * NT + i0 + lane];
  float wv0 = wsdl[b0 * NT + i0 + lane], wv1 = wsdl[(b0 + 1) * NT + i0 + lane];
  float uv = u2[i0 + lane];

  {
    float um = fmaxf(uv, 0.f);
#pragma unroll
    for (int off = 32; off > 0; off >>= 1) um = fmaxf(um, __shfl_down(um, off, 64));
    if (lane == 0) finU[wid] = um;
  }
  __syncthreads();
  float up = finU[0];
#pragma unroll
  for (int w = 1; w < 16; ++w) up = fmaxf(up, finU[w]);

  float mh0 = fmaxf(rc0 * fmaf(wb0, gd, uc), fmaf(wb0, gof, up));
  float mh1 = fmaxf(rc1 * fmaf(wb1, gd, uc), fmaf(wb1, gof, up));

  float d0 = 0.f, d1 = 0.f;
#pragma unroll 8
  for (int ii = 0; ii < 64; ++ii) {
    float g = G2[(i0 + ii) * NT + c];
    float su = rdlane(uv, ii);
    float s0 = rdlane(rv0, ii), s1 = rdlane(rv1, ii);
    d0 += EXP2F(fmaf(s0, fmaf(wb0, g, su), -mh0));
    d1 += EXP2F(fmaf(s1, fmaf(wb1, g, su), -mh1));
  }
  RA[q][c] = d0;
  RB[q][c] = d1;
  __syncthreads();
  if (q == 0) {
    float2 L;
    L.x = mh0 + LOG2F(RA[0][c] + RA[1][c] + RA[2][c] + RA[3][c]);
    L.y = mh1 + LOG2F(RB[0][c] + RB[1][c] + RB[2][c] + RB[3][c]);
    L2s[c] = L;
  }
  __syncthreads();
  float2 Lq = L2s[i0 + lane];
  float Lv0 = Lq.x, Lv1 = Lq.y;

  float S0 = 0.f, S1 = 0.f;
#pragma unroll 8
  for (int jj = 0; jj < 64; ++jj) {
    float g = G2[(i0 + jj) * NT + c];
    float w0 = rdlane(wv0, jj), w1 = rdlane(wv1, jj);
    float l0 = rdlane(Lv0, jj), l1 = rdlane(Lv1, jj);
    S0 += EXP2F(fmaf(rc0, fmaf(w0, g, uc), -l0));
    S1 += EXP2F(fmaf(rc1, fmaf(w1, g, uc), -l1));
  }
  RA[q][c] = S0;
  RB[q][c] = S1;
  __syncthreads();
  if (q == 0) {
    float2 qv;
    qv.x = (RA[0][c] + RA[1][c] + RA[2][c] + RA[3][c]) * rc0;
    qv.y = (RB[0][c] + RB[1][c] + RB[2][c] + RB[3][c]) * rc1;
    Q2s[c] = qv;
  }
  __syncthreads();
  float2 Qq = Q2s[i0 + lane];
  float Qv0 = Qq.x, Qv1 = Qq.y;

  float a0 = 0.f, a1 = 0.f, y0 = 0.f, y1 = 0.f;
#pragma unroll 8
  for (int tt = 0; tt < 64; ++tt) {
    float mk = Mrow[(i0 + tt) * NT + c];
    float s0 = rdlane(rv0, tt), s1 = rdlane(rv1, tt);
    float p0 = rdlane(Qv0, tt), p1 = rdlane(Qv1, tt);
    a0 = fmaf(s0, mk, a0);
    a1 = fmaf(s1, mk, a1);
    y0 = fmaf(p0, mk, y0);
    y1 = fmaf(p1, mk, y1);
  }
  RA[q][c] = a0;
  RB[q][c] = a1;
  RC[q][c] = y0;
  RD[q][c] = y1;
  __syncthreads();
  float st[6];
  {
    float bfc = bf[c];
    const float invT = 1.0f / NT;
    float avr0 = fmaf(RA[0][c] + RA[1][c] + RA[2][c] + RA[3][c], invT, bfc);
    float avr1 = fmaf(RB[0][c] + RB[1][c] + RB[2][c] + RB[3][c], invT, bfc);
    float avw0 = fmaf(RC[0][c] + RC[1][c] + RC[2][c] + RC[3][c], invT, bfc);
    float avw1 = fmaf(RD[0][c] + RD[1][c] + RD[2][c] + RD[3][c], invT, bfc);
    st[0] = avr0 * avw0; st[1] = avr0 * avr0; st[2] = avw0 * avw0;
    st[3] = avr1 * avw1; st[4] = avr1 * avr1; st[5] = avw1 * avw1;
  }
#pragma unroll
  for (int k = 0; k < 6; ++k)
#pragma unroll
    for (int off = 32; off > 0; off >>= 1) st[k] += __shfl_down(st[k], off, 64);
  if (lane == 0)
#pragma unroll
    for (int k = 0; k < 6; ++k) fin[wid][k] = st[k];
  __syncthreads();
  if (tid < NBATCH) {
    int bb = tid;
    float N = 0.f, A = 0.f, C = 0.f;
    for (int w = 0; w < 16; ++w) {
      N += fin[w][3 * bb + 0];
      A += fin[w][3 * bb + 1];
      C += fin[w][3 * bb + 2];
    }
    out[b0 + bb] = N / fmaxf(sqrtf(A) * sqrtf(C), 1e-8f) * 3.0f;
  }
}

extern "C" void kernel_launch(void* const* d_in, const int* in_sizes, int n_in,
                              void* d_out, int out_size, void* d_ws, size_t ws_size,
                              hipStream_t stream) {
  const float* req  = (const float*)d_in[0];
  const float* wsdl = (const float*)d_in[1];
  const float* TE   = (const float*)d_in[2];
  const float* wf   = (const float*)d_in[3];
  const float* bf   = (const float*)d_in[4];
  float* out = (float*)d_out;

  // ws: [Mt | Mrow | G2 | u2 | Gd | Gof]
  float* Mt   = (float*)d_ws;
  float* Mrow = Mt + NT * NT;
  float* G2   = Mrow + NT * NT;
  float* u2   = G2 + NT * NT;
  float* Gd   = u2 + NT;
  float* Gof  = Gd + NT;

  void* args[] = {(void*)&req, (void*)&wsdl, (void*)&TE, (void*)&wf,
                  (void*)&bf,  (void*)&Mt,   (void*)&Mrow, (void*)&G2,
                  (void*)&u2,  (void*)&Gd,   (void*)&Gof,  (void*)&out};
  hipError_t err = hipLaunchCooperativeKernel(
      (const void*)k_all, dim3(NB / NBATCH), dim3(1024), args, 0, stream);
  if (err != hipSuccess) {
    // Benign validation failure (e.g. cooperative grid too large): proven path.
    k_M<<<NT, 1024, 0, stream>>>(TE, wf, Mt, Mrow);
    k_G<<<NT, 1024, 0, stream>>>(Mt, Mrow, bf, G2, u2, Gd, Gof);
    k_main<<<NB / NBATCH, 1024, 0, stream>>>(req, wsdl, Mrow, G2, u2, Gd, Gof,
                                             bf, out);
  }
}

// Round 2
// 106.163 us; speedup vs baseline: 2.3303x; 2.3303x over previous
//
#include <hip/hip_runtime.h>
#include <math.h>

constexpr int NB = 1024;   // batch
constexpr int NT = 256;    // topic_size
constexpr int NE = 300;    // embedding_size
constexpr int NBATCH = 2;  // batches per k_main block

typedef float f32x2 __attribute__((ext_vector_type(2)));
typedef float f32x4 __attribute__((ext_vector_type(4)));

#if defined(__has_builtin)
#if __has_builtin(__builtin_amdgcn_exp2f)
#define EXP2F(x) __builtin_amdgcn_exp2f(x)
#else
#define EXP2F(x) exp2f(x)
#endif
#if __has_builtin(__builtin_amdgcn_logf)
#define LOG2F(x) __builtin_amdgcn_logf(x)
#else
#define LOG2F(x) log2f(x)
#endif
#else
#define EXP2F(x) exp2f(x)
#define LOG2F(x) log2f(x)
#endif

__device__ __forceinline__ float rdlane(float v, int l) {
  return __uint_as_float(__builtin_amdgcn_readlane(__float_as_uint(v), l));
}

// ===== packed f32 FMA helpers (VOP3P). D = S0*S1 + S2 per 32-bit lane.
// op_sel[i] selects which half of src i feeds the LOW result;
// op_sel_hi[i] selects which half feeds the HIGH result.
// Defaults (plain): op_sel [0,0,0], op_sel_hi [1,1,1].
__device__ __forceinline__ f32x2 pk_fma(f32x2 a, f32x2 b, f32x2 c) {
  f32x2 d;
  asm("v_pk_fma_f32 %0, %1, %2, %3" : "=v"(d) : "v"(a), "v"(b), "v"(c));
  return d;
}
// src0 broadcast: both result halves use a.x (alo) or a.y (ahi)
__device__ __forceinline__ f32x2 pk_fma_alo(f32x2 a, f32x2 b, f32x2 c) {
  f32x2 d;
  asm("v_pk_fma_f32 %0, %1, %2, %3 op_sel:[0,0,0] op_sel_hi:[0,1,1]"
      : "=v"(d) : "v"(a), "v"(b), "v"(c));
  return d;
}
__device__ __forceinline__ f32x2 pk_fma_ahi(f32x2 a, f32x2 b, f32x2 c) {
  f32x2 d;
  asm("v_pk_fma_f32 %0, %1, %2, %3 op_sel:[1,0,0] op_sel_hi:[1,1,1]"
      : "=v"(d) : "v"(a), "v"(b), "v"(c));
  return d;
}
// src1 broadcast: both halves use b.x / b.y
__device__ __forceinline__ f32x2 pk_fma_blo(f32x2 a, f32x2 b, f32x2 c) {
  f32x2 d;
  asm("v_pk_fma_f32 %0, %1, %2, %3 op_sel:[0,0,0] op_sel_hi:[1,0,1]"
      : "=v"(d) : "v"(a), "v"(b), "v"(c));
  return d;
}
__device__ __forceinline__ f32x2 pk_fma_bhi(f32x2 a, f32x2 b, f32x2 c) {
  f32x2 d;
  asm("v_pk_fma_f32 %0, %1, %2, %3 op_sel:[0,1,0] op_sel_hi:[1,1,1]"
      : "=v"(d) : "v"(a), "v"(b), "v"(c));
  return d;
}
// src2 broadcast: both halves use c.x / c.y
__device__ __forceinline__ f32x2 pk_fma_clo(f32x2 a, f32x2 b, f32x2 c) {
  f32x2 d;
  asm("v_pk_fma_f32 %0, %1, %2, %3 op_sel:[0,0,0] op_sel_hi:[1,1,0]"
      : "=v"(d) : "v"(a), "v"(b), "v"(c));
  return d;
}
__device__ __forceinline__ f32x2 pk_fma_chi(f32x2 a, f32x2 b, f32x2 c) {
  f32x2 d;
  asm("v_pk_fma_f32 %0, %1, %2, %3 op_sel:[0,0,1] op_sel_hi:[1,1,1]"
      : "=v"(d) : "v"(a), "v"(b), "v"(c));
  return d;
}

// ===== k_M: column blk of M. Mt[blk][t]=sum_e TE[e,t]*wf[blk,e].  (r7, proven)
__global__ __launch_bounds__(1024) void k_M(const float* __restrict__ TE,
                                            const float* __restrict__ wf,
                                            float* __restrict__ Mt,
                                            float* __restrict__ Mrow) {
  __shared__ float red[4][NT];
  int tid = threadIdx.x;
  int q = __builtin_amdgcn_readfirstlane(tid >> 8);
  int c = tid & 255, lane = tid & 63, blk = blockIdx.x;

  const float* wrow = wf + blk * NE;
  float4 wa = *(const float4*)(wrow + 4 * lane);
  float4 wb = make_float4(0.f, 0.f, 0.f, 0.f);
  if (lane < 11) wb = *(const float4*)(wrow + 256 + 4 * lane);
  float acc = 0.f;
#pragma unroll
  for (int k = 0; k < 16; ++k) {  // chunks q+4k <= 63
    int ec = q + 4 * k;
    float wx = rdlane(wa.x, ec), wy = rdlane(wa.y, ec);
    float wz = rdlane(wa.z, ec), ww = rdlane(wa.w, ec);
    const float* tp = TE + 4 * ec * NT + c;
    acc = fmaf(tp[0], wx, acc);
    acc = fmaf(tp[NT], wy, acc);
    acc = fmaf(tp[2 * NT], wz, acc);
    acc = fmaf(tp[3 * NT], ww, acc);
  }
#pragma unroll
  for (int k = 16; k < 19; ++k) {  // chunks 64..74
    int ec = q + 4 * k;
    if (ec < 75) {  // wave-uniform
      int l = ec - 64;
      float wx = rdlane(wb.x, l), wy = rdlane(wb.y, l);
      float wz = rdlane(wb.z, l), ww = rdlane(wb.w, l);
      const float* tp = TE + 4 * ec * NT + c;
      acc = fmaf(tp[0], wx, acc);
      acc = fmaf(tp[NT], wy, acc);
      acc = fmaf(tp[2 * NT], wz, acc);
      acc = fmaf(tp[3 * NT], ww, acc);
    }
  }
  red[q][c] = acc;
  __syncthreads();
  if (q == 0) {
    float s = red[0][c] + red[1][c] + red[2][c] + red[3][c];
    Mt[blk * NT + c] = s;    // coalesced
    Mrow[c * NT + blk] = s;  // scattered, one-time
  }
}

// ===== k_G: row blk of G2=(M M^T)*log2e; Gd (diag), Gof (off-diag row max,
// clamped >=0), u2=(M bf)*log2e.  (r7, proven)
__global__ __launch_bounds__(1024) void k_G(const float* __restrict__ Mt,
                                            const float* __restrict__ Mrow,
                                            const float* __restrict__ bf,
                                            float* __restrict__ G2,
                                            float* __restrict__ u2,
                                            float* __restrict__ Gd,
                                            float* __restrict__ Gof) {
  __shared__ float red[4][NT];
  __shared__ float fin2[4][2];
  const float LOG2E = 1.4426950408889634f;
  int tid = threadIdx.x;
  int q = __builtin_amdgcn_readfirstlane(tid >> 8);
  int c = tid & 255, lane = tid & 63, wid = tid >> 6, blk = blockIdx.x;

  const float* mrowp = Mrow + blk * NT;
  float4 ma = *(const float4*)(mrowp + 4 * lane);
  float acc = 0.f;
  int c0 = q * 16;
#pragma unroll
  for (int k = 0; k < 16; ++k) {
    int fc = c0 + k;  // SGPR
    float mx = rdlane(ma.x, fc), my = rdlane(ma.y, fc);
    float mz = rdlane(ma.z, fc), mw = rdlane(ma.w, fc);
    const float* tp = Mt + 4 * fc * NT + c;
    acc = fmaf(tp[0], mx, acc);
    acc = fmaf(tp[NT], my, acc);
    acc = fmaf(tp[2 * NT], mz, acc);
    acc = fmaf(tp[3 * NT], mw, acc);
  }
  red[q][c] = acc;
  __syncthreads();
  if (q == 0) {
    float g = (red[0][c] + red[1][c] + red[2][c] + red[3][c]) * LOG2E;
    G2[blk * NT + c] = g;
    if (c == blk) Gd[blk] = g;
    float v = (c == blk) ? -3.0e38f : g;
#pragma unroll
    for (int off = 32; off > 0; off >>= 1) v = fmaxf(v, __shfl_down(v, off, 64));
    if (lane == 0) fin2[wid][0] = v;
    float p = mrowp[c] * bf[c];  // coalesced
#pragma unroll
    for (int off = 32; off > 0; off >>= 1) p += __shfl_down(p, off, 64);
    if (lane == 0) fin2[wid][1] = p;
  }
  __syncthreads();
  if (tid == 0) {
    float gof = fmaxf(fmaxf(fin2[0][0], fin2[1][0]), fmaxf(fin2[2][0], fin2[3][0]));
    Gof[blk] = fmaxf(gof, 0.f);
    u2[blk] = (fin2[0][1] + fin2[1][1] + fin2[2][1] + fin2[3][1]) * LOG2E;
  }
}

// ===== k_main: packed-f32 rewrite.
// Thread layout: cp = tid&127 owns column PAIR (2cp, 2cp+1); q = tid>>7 in
// [0,8) owns 32 reduction indices.  Loop scalars come from LDS b64 broadcast
// reads (wave-uniform addr -> conflict-free) straight into even VGPR pairs;
// VOP3P op_sel broadcasts lo/hi halves with ZERO mov overhead (vs r8's
// batch-axis float2 packing which spilled).  float2 global loads halve vmem.
// L stored NEGATED in LDS so no neg modifiers needed.
__global__ __launch_bounds__(1024, 8) void k_main(
    const float* __restrict__ req, const float* __restrict__ wsdl,
    const float* __restrict__ Mrow, const float* __restrict__ G2,
    const float* __restrict__ u2, const float* __restrict__ Gd,
    const float* __restrict__ Gof, const float* __restrict__ bf,
    float* __restrict__ out) {
  __shared__ f32x4 sArr[NT];       // (r0_i, r1_i, u_i, u_i)           4 KB
  __shared__ f32x4 WL[NT];         // (w0_j, w1_j, -L0_j, -L1_j)       4 KB
  __shared__ f32x2 QArr[NT];       // (Qv0_t, Qv1_t)                   2 KB
  __shared__ f32x2 RR[4][8][128];  // 8-way cross-quad reductions     32 KB
  __shared__ float finU[16];
  __shared__ float fin[16][6];

  int tid = threadIdx.x;
  int cp = tid & 127, q = tid >> 7;  // q wave-uniform (2 waves per quad)
  int c2 = cp * 2;
  int lane = tid & 63, wid = tid >> 6;
  int blk = blockIdx.x, b0 = blk * NBATCH, i0 = q * 32;

  // ---- stage loop-scalar arrays into LDS (one pass, coalesced) ----
  if (tid < NT) {
    float r0 = req[b0 * NT + tid], r1 = req[(b0 + 1) * NT + tid];
    float u = u2[tid];
    sArr[tid] = (f32x4){r0, r1, u, u};
    float w0 = wsdl[b0 * NT + tid], w1 = wsdl[(b0 + 1) * NT + tid];
    *reinterpret_cast<f32x2*>(&WL[tid]) = (f32x2){w0, w1};
  }

  // ---- per-thread column-pair constants (8B-aligned float2 loads) ----
  f32x2 wb0P = *(const f32x2*)(wsdl + b0 * NT + c2);
  f32x2 wb1P = *(const f32x2*)(wsdl + (b0 + 1) * NT + c2);
  f32x2 rc0P = *(const f32x2*)(req + b0 * NT + c2);
  f32x2 rc1P = *(const f32x2*)(req + (b0 + 1) * NT + c2);
  f32x2 ucP = *(const f32x2*)(u2 + c2);
  f32x2 gdP = *(const f32x2*)(Gd + c2);
  f32x2 gofP = *(const f32x2*)(Gof + c2);

  // up = max_i max(u_i, 0)
  {
    float um = fmaxf(u2[tid & 255], 0.f);
#pragma unroll
    for (int off = 32; off > 0; off >>= 1) um = fmaxf(um, __shfl_down(um, off, 64));
    if (lane == 0) finU[wid] = um;
  }
  __syncthreads();  // also covers sArr/WL staging
  float up = finU[0];
#pragma unroll
  for (int w = 1; w < 16; ++w) up = fmaxf(up, finU[w]);

  // Safe softmax upper bound per (batch, column) — same formula as proven r7.
  float mh00 = fmaxf(rc0P.x * fmaf(wb0P.x, gdP.x, ucP.x), fmaf(wb0P.x, gofP.x, up));
  float mh01 = fmaxf(rc0P.y * fmaf(wb0P.y, gdP.y, ucP.y), fmaf(wb0P.y, gofP.y, up));
  float mh10 = fmaxf(rc1P.x * fmaf(wb1P.x, gdP.x, ucP.x), fmaf(wb1P.x, gofP.x, up));
  float mh11 = fmaxf(rc1P.y * fmaf(wb1P.y, gdP.y, ucP.y), fmaf(wb1P.y, gofP.y, up));
  f32x2 mhn0 = (f32x2){-mh00, -mh01};
  f32x2 mhn1 = (f32x2){-mh10, -mh11};

  const float* gbase = G2 + c2 + i0 * NT;
  const float* mbase = Mrow + c2 + i0 * NT;

  // ---- Pass D: column denominators (4 elems/iter: 2 cols x 2 batches) ----
  float d00 = 0.f, d01 = 0.f, d10 = 0.f, d11 = 0.f;
#pragma unroll 8
  for (int ii = 0; ii < 32; ++ii) {
    f32x2 gP = *(const f32x2*)(gbase + ii * NT);
    const f32x2* sp = (const f32x2*)(sArr + i0 + ii);
    f32x2 s01 = sp[0], suP = sp[1];
    f32x2 t0 = pk_fma(wb0P, gP, suP);          // wb0*g + u  (per col)
    f32x2 t1 = pk_fma(wb1P, gP, suP);
    f32x2 p0 = pk_fma_alo(s01, t0, mhn0);      // r0_i*t0 - mh0
    f32x2 p1 = pk_fma_ahi(s01, t1, mhn1);      // r1_i*t1 - mh1
    d00 += EXP2F(p0.x); d01 += EXP2F(p0.y);
    d10 += EXP2F(p1.x); d11 += EXP2F(p1.y);
  }
  RR[0][q][cp] = (f32x2){d00, d01};
  RR[1][q][cp] = (f32x2){d10, d11};
  __syncthreads();
  // L (negated) per (batch=q<2, col pair); scalar stores avoid vector RMW race
  if (q < 2) {
    f32x2 S = RR[q][0][cp];
#pragma unroll
    for (int k = 1; k < 8; ++k) S += RR[q][k][cp];
    f32x2 mhnb = (q == 0) ? mhn0 : mhn1;
    float nl0 = mhnb.x - LOG2F(S.x);
    float nl1 = mhnb.y - LOG2F(S.y);
    ((float*)(WL + c2))[2 + q] = nl0;
    ((float*)(WL + c2 + 1))[2 + q] = nl1;
  }
  __syncthreads();

  // ---- Pass S: row-sums of softmaxed att (rows c2,c2+1), j over quad ----
  float S00 = 0.f, S01 = 0.f, S10 = 0.f, S11 = 0.f;
#pragma unroll 8
  for (int jj = 0; jj < 32; ++jj) {
    f32x2 gP = *(const f32x2*)(gbase + jj * NT);  // G[c][j] by symmetry
    const f32x2* wp = (const f32x2*)(WL + i0 + jj);
    f32x2 w01 = wp[0], l01 = wp[1];               // l01 holds -L
    f32x2 t0 = pk_fma_blo(gP, w01, ucP);          // g*w0_j + uc
    f32x2 t1 = pk_fma_bhi(gP, w01, ucP);          // g*w1_j + uc
    f32x2 p0 = pk_fma_clo(rc0P, t0, l01);         // rc0*t0 - L0_j
    f32x2 p1 = pk_fma_chi(rc1P, t1, l01);         // rc1*t1 - L1_j
    S00 += EXP2F(p0.x); S01 += EXP2F(p0.y);
    S10 += EXP2F(p1.x); S11 += EXP2F(p1.y);
  }
  RR[0][q][cp] = (f32x2){S00, S01};
  RR[1][q][cp] = (f32x2){S10, S11};
  __syncthreads();
  if (q < 2) {
    f32x2 S = RR[q][0][cp];
#pragma unroll
    for (int k = 1; k < 8; ++k) S += RR[q][k][cp];
    f32x2 rcb = (q == 0) ? rc0P : rc1P;
    ((float*)(QArr + c2))[q] = S.x * rcb.x;
    ((float*)(QArr + c2 + 1))[q] = S.y * rcb.y;
  }
  __syncthreads();

  // ---- Pass B: ave_req = (r/T)@M + bf, ave_wsdl = (qv/T)@M + bf ----
  f32x2 a0 = (f32x2){0.f, 0.f}, a1 = a0, y0 = a0, y1 = a0;
#pragma unroll 8
  for (int tt = 0; tt < 32; ++tt) {
    f32x2 mkP = *(const f32x2*)(mbase + tt * NT);
    const f32x2* sp = (const f32x2*)(sArr + i0 + tt);
    f32x2 s01 = sp[0];
    f32x2 q01 = QArr[i0 + tt];
    a0 = pk_fma_alo(s01, mkP, a0);
    a1 = pk_fma_ahi(s01, mkP, a1);
    y0 = pk_fma_alo(q01, mkP, y0);
    y1 = pk_fma_ahi(q01, mkP, y1);
  }
  RR[0][q][cp] = a0;
  RR[1][q][cp] = a1;
  RR[2][q][cp] = y0;
  RR[3][q][cp] = y1;
  __syncthreads();

  // ---- final stats: 8-way sums (replicated across q; 8x factor cancels) ----
  f32x2 A0 = RR[0][0][cp], A1 = RR[1][0][cp], Y0 = RR[2][0][cp], Y1 = RR[3][0][cp];
#pragma unroll
  for (int k = 1; k < 8; ++k) {
    A0 += RR[0][k][cp];
    A1 += RR[1][k][cp];
    Y0 += RR[2][k][cp];
    Y1 += RR[3][k][cp];
  }
  float st[6];
  {
    f32x2 bfP = *(const f32x2*)(bf + c2);
    const float invT = 1.0f / NT;
    f32x2 avr0, avr1, avw0, avw1;
    avr0.x = fmaf(A0.x, invT, bfP.x); avr0.y = fmaf(A0.y, invT, bfP.y);
    avr1.x = fmaf(A1.x, invT, bfP.x); avr1.y = fmaf(A1.y, invT, bfP.y);
    avw0.x = fmaf(Y0.x, invT, bfP.x); avw0.y = fmaf(Y0.y, invT, bfP.y);
    avw1.x = fmaf(Y1.x, invT, bfP.x); avw1.y = fmaf(Y1.y, invT, bfP.y);
    st[0] = fmaf(avr0.y, avw0.y, avr0.x * avw0.x);
    st[1] = fmaf(avr0.y, avr0.y, avr0.x * avr0.x);
    st[2] = fmaf(avw0.y, avw0.y, avw0.x * avw0.x);
    st[3] = fmaf(avr1.y, avw1.y, avr1.x * avw1.x);
    st[4] = fmaf(avr1.y, avr1.y, avr1.x * avr1.x);
    st[5] = fmaf(avw1.y, avw1.y, avw1.x * avw1.x);
  }
#pragma unroll
  for (int k = 0; k < 6; ++k)
#pragma unroll
    for (int off = 32; off > 0; off >>= 1) st[k] += __shfl_down(st[k], off, 64);
  if (lane == 0)
#pragma unroll
    for (int k = 0; k < 6; ++k) fin[wid][k] = st[k];
  __syncthreads();
  if (tid < NBATCH) {
    int bb = tid;
    float N = 0.f, A = 0.f, C = 0.f;
    for (int w = 0; w < 16; ++w) {
      N += fin[w][3 * bb + 0];
      A += fin[w][3 * bb + 1];
      C += fin[w][3 * bb + 2];
    }
    out[b0 + bb] = N / fmaxf(sqrtf(A) * sqrtf(C), 1e-8f) * 3.0f;
  }
}

extern "C" void kernel_launch(void* const* d_in, const int* in_sizes, int n_in,
                              void* d_out, int out_size, void* d_ws, size_t ws_size,
                              hipStream_t stream) {
  const float* req  = (const float*)d_in[0];
  const float* wsdl = (const float*)d_in[1];
  const float* TE   = (const float*)d_in[2];
  const float* wf   = (const float*)d_in[3];
  const float* bf   = (const float*)d_in[4];
  float* out = (float*)d_out;

  // ws: [Mt | Mrow | G2 | u2 | Gd | Gof]
  float* Mt   = (float*)d_ws;
  float* Mrow = Mt + NT * NT;
  float* G2   = Mrow + NT * NT;
  float* u2   = G2 + NT * NT;
  float* Gd   = u2 + NT;
  float* Gof  = Gd + NT;

  k_M<<<NT, 1024, 0, stream>>>(TE, wf, Mt, Mrow);
  k_G<<<NT, 1024, 0, stream>>>(Mt, Mrow, bf, G2, u2, Gd, Gof);
  k_main<<<NB / NBATCH, 1024, 0, stream>>>(req, wsdl, Mrow, G2, u2, Gd, Gof,
                                           bf, out);
}

// Round 4
// 102.701 us; speedup vs baseline: 2.4089x; 1.0337x over previous
//
#include <hip/hip_runtime.h>
#include <math.h>

constexpr int NB = 1024;   // batch
constexpr int NT = 256;    // topic_size
constexpr int NE = 300;    // embedding_size

typedef float f32x2 __attribute__((ext_vector_type(2)));
typedef float f32x4 __attribute__((ext_vector_type(4)));

#if defined(__has_builtin)
#if __has_builtin(__builtin_amdgcn_exp2f)
#define EXP2F(x) __builtin_amdgcn_exp2f(x)
#else
#define EXP2F(x) exp2f(x)
#endif
#if __has_builtin(__builtin_amdgcn_logf)
#define LOG2F(x) __builtin_amdgcn_logf(x)
#else
#define LOG2F(x) log2f(x)
#endif
#else
#define EXP2F(x) exp2f(x)
#define LOG2F(x) log2f(x)
#endif

__device__ __forceinline__ float rdlane(float v, int l) {
  return __uint_as_float(__builtin_amdgcn_readlane(__float_as_uint(v), l));
}

// ===== packed f32 FMA helpers (VOP3P).
// op_sel[i] selects the half of src i feeding the LOW result;
// op_sel_hi[i] selects the half feeding the HIGH result.
// src0 broadcast of a.x to both halves:
__device__ __forceinline__ f32x2 pk_fma_alo(f32x2 a, f32x2 b, f32x2 c) {
  f32x2 d;
  asm("v_pk_fma_f32 %0, %1, %2, %3 op_sel:[0,0,0] op_sel_hi:[0,1,1]"
      : "=v"(d) : "v"(a), "v"(b), "v"(c));
  return d;
}
// src0 broadcast of a.y:
__device__ __forceinline__ f32x2 pk_fma_ahi(f32x2 a, f32x2 b, f32x2 c) {
  f32x2 d;
  asm("v_pk_fma_f32 %0, %1, %2, %3 op_sel:[1,0,0] op_sel_hi:[1,1,1]"
      : "=v"(d) : "v"(a), "v"(b), "v"(c));
  return d;
}
// src2 broadcast of c.y:
__device__ __forceinline__ f32x2 pk_fma_chi(f32x2 a, f32x2 b, f32x2 c) {
  f32x2 d;
  asm("v_pk_fma_f32 %0, %1, %2, %3 op_sel:[0,0,1] op_sel_hi:[1,1,1]"
      : "=v"(d) : "v"(a), "v"(b), "v"(c));
  return d;
}

// ===== k_M: column blk of M. Mt[blk][t]=sum_e TE[e,t]*wf[blk,e].  (proven)
__global__ __launch_bounds__(1024) void k_M(const float* __restrict__ TE,
                                            const float* __restrict__ wf,
                                            float* __restrict__ Mt,
                                            float* __restrict__ Mrow) {
  __shared__ float red[4][NT];
  int tid = threadIdx.x;
  int q = __builtin_amdgcn_readfirstlane(tid >> 8);
  int c = tid & 255, lane = tid & 63, blk = blockIdx.x;

  const float* wrow = wf + blk * NE;
  float4 wa = *(const float4*)(wrow + 4 * lane);
  float4 wb = make_float4(0.f, 0.f, 0.f, 0.f);
  if (lane < 11) wb = *(const float4*)(wrow + 256 + 4 * lane);
  float acc = 0.f;
#pragma unroll
  for (int k = 0; k < 16; ++k) {  // chunks q+4k <= 63
    int ec = q + 4 * k;
    float wx = rdlane(wa.x, ec), wy = rdlane(wa.y, ec);
    float wz = rdlane(wa.z, ec), ww = rdlane(wa.w, ec);
    const float* tp = TE + 4 * ec * NT + c;
    acc = fmaf(tp[0], wx, acc);
    acc = fmaf(tp[NT], wy, acc);
    acc = fmaf(tp[2 * NT], wz, acc);
    acc = fmaf(tp[3 * NT], ww, acc);
  }
#pragma unroll
  for (int k = 16; k < 19; ++k) {  // chunks 64..74
    int ec = q + 4 * k;
    if (ec < 75) {  // wave-uniform
      int l = ec - 64;
      float wx = rdlane(wb.x, l), wy = rdlane(wb.y, l);
      float wz = rdlane(wb.z, l), ww = rdlane(wb.w, l);
      const float* tp = TE + 4 * ec * NT + c;
      acc = fmaf(tp[0], wx, acc);
      acc = fmaf(tp[NT], wy, acc);
      acc = fmaf(tp[2 * NT], wz, acc);
      acc = fmaf(tp[3 * NT], ww, acc);
    }
  }
  red[q][c] = acc;
  __syncthreads();
  if (q == 0) {
    float s = red[0][c] + red[1][c] + red[2][c] + red[3][c];
    Mt[blk * NT + c] = s;    // coalesced
    Mrow[c * NT + blk] = s;  // scattered, one-time
  }
}

// ===== k_G: row blk of G2=(M M^T)*log2e; Gd, Gof, u2.  (proven)
__global__ __launch_bounds__(1024) void k_G(const float* __restrict__ Mt,
                                            const float* __restrict__ Mrow,
                                            const float* __restrict__ bf,
                                            float* __restrict__ G2,
                                            float* __restrict__ u2,
                                            float* __restrict__ Gd,
                                            float* __restrict__ Gof) {
  __shared__ float red[4][NT];
  __shared__ float fin2[4][2];
  const float LOG2E = 1.4426950408889634f;
  int tid = threadIdx.x;
  int q = __builtin_amdgcn_readfirstlane(tid >> 8);
  int c = tid & 255, lane = tid & 63, wid = tid >> 6, blk = blockIdx.x;

  const float* mrowp = Mrow + blk * NT;
  float4 ma = *(const float4*)(mrowp + 4 * lane);
  float acc = 0.f;
  int c0 = q * 16;
#pragma unroll
  for (int k = 0; k < 16; ++k) {
    int fc = c0 + k;  // SGPR
    float mx = rdlane(ma.x, fc), my = rdlane(ma.y, fc);
    float mz = rdlane(ma.z, fc), mw = rdlane(ma.w, fc);
    const float* tp = Mt + 4 * fc * NT + c;
    acc = fmaf(tp[0], mx, acc);
    acc = fmaf(tp[NT], my, acc);
    acc = fmaf(tp[2 * NT], mz, acc);
    acc = fmaf(tp[3 * NT], mw, acc);
  }
  red[q][c] = acc;
  __syncthreads();
  if (q == 0) {
    float g = (red[0][c] + red[1][c] + red[2][c] + red[3][c]) * LOG2E;
    G2[blk * NT + c] = g;
    if (c == blk) Gd[blk] = g;
    float v = (c == blk) ? -3.0e38f : g;
#pragma unroll
    for (int off = 32; off > 0; off >>= 1) v = fmaxf(v, __shfl_down(v, off, 64));
    if (lane == 0) fin2[wid][0] = v;
    float p = mrowp[c] * bf[c];  // coalesced
#pragma unroll
    for (int off = 32; off > 0; off >>= 1) p += __shfl_down(p, off, 64);
    if (lane == 0) fin2[wid][1] = p;
  }
  __syncthreads();
  if (tid == 0) {
    float gof = fmaxf(fmaxf(fin2[0][0], fin2[1][0]), fmaxf(fin2[2][0], fin2[3][0]));
    Gof[blk] = fmaxf(gof, 0.f);
    u2[blk] = (fin2[0][1] + fin2[1][1] + fin2[2][1] + fin2[3][1]) * LOG2E;
  }
}

// ===== k_main: 512 threads (8 waves), 1 batch/block, grid 1024.
// 4 blocks/CU (LDS ~23 KB) -> 4 independent barrier domains per CU to fill
// the stall bubbles R2 exposed (VALUBusy 37.5%).  Column QUADS via dwordx4
// loads halve vmem + LDS-broadcast instruction counts.  Inner math is
// bit-identical to the proven R2 kernel (same fma pairings + reduction
// trees); only the final cosine-stat order changes.
__global__ __launch_bounds__(512, 8) void k_main(
    const float* __restrict__ req, const float* __restrict__ wsdl,
    const float* __restrict__ Mrow, const float* __restrict__ G2,
    const float* __restrict__ u2, const float* __restrict__ Gd,
    const float* __restrict__ Gof, const float* __restrict__ bf,
    float* __restrict__ out) {
  __shared__ f32x2 sArr[NT];       // (r_i, u_i)                      2 KB
  __shared__ f32x2 WL[NT];         // (w_j, nL_j)  nL = -L            2 KB
  __shared__ f32x2 QB[NT];         // (r_t, Q_t)                      2 KB
  __shared__ f32x4 MHN4[64];       // -mh per column                  1 KB
  __shared__ f32x4 RRB[2][8][64];  // 8-way cross-wave partials      16 KB
  __shared__ float finU[4];
  __shared__ float fin[4][3];

  int tid = threadIdx.x;
  int cq = tid & 63, q = tid >> 6;  // q == wave id; wave-uniform
  int c4 = cq * 4;
  int b = blockIdx.x, i0 = q * 32;

  // ---- stage loop-scalar arrays + up partials (waves 0-3) ----
  if (tid < NT) {
    float r = req[b * NT + tid];
    float u = u2[tid];
    sArr[tid] = (f32x2){r, u};
    WL[tid] = (f32x2){wsdl[b * NT + tid], 0.f};
    float um = fmaxf(u, 0.f);
#pragma unroll
    for (int off = 32; off > 0; off >>= 1) um = fmaxf(um, __shfl_down(um, off, 64));
    if ((tid & 63) == 0) finU[tid >> 6] = um;
  }

  // ---- per-thread column-quad constants (dwordx4) ----
  f32x4 rcP = *(const f32x4*)(req + b * NT + c4);
  f32x4 wbP = *(const f32x4*)(wsdl + b * NT + c4);
  f32x4 ucP = *(const f32x4*)(u2 + c4);
  f32x4 gdP = *(const f32x4*)(Gd + c4);
  f32x4 gofP = *(const f32x4*)(Gof + c4);

  __syncthreads();  // staging + finU ready
  float up = fmaxf(fmaxf(finU[0], finU[1]), fmaxf(finU[2], finU[3]));

  // Safe softmax upper bound per column (proven formula).
  f32x4 mhn;
  mhn.x = -fmaxf(rcP.x * fmaf(wbP.x, gdP.x, ucP.x), fmaf(wbP.x, gofP.x, up));
  mhn.y = -fmaxf(rcP.y * fmaf(wbP.y, gdP.y, ucP.y), fmaf(wbP.y, gofP.y, up));
  mhn.z = -fmaxf(rcP.z * fmaf(wbP.z, gdP.z, ucP.z), fmaf(wbP.z, gofP.z, up));
  mhn.w = -fmaxf(rcP.w * fmaf(wbP.w, gdP.w, ucP.w), fmaf(wbP.w, gofP.w, up));
  if (q == 0) MHN4[cq] = mhn;  // covered by post-D barrier

  f32x2 wb01 = (f32x2){wbP.x, wbP.y}, wb23 = (f32x2){wbP.z, wbP.w};
  f32x2 rc01 = (f32x2){rcP.x, rcP.y}, rc23 = (f32x2){rcP.z, rcP.w};
  f32x2 uc01 = (f32x2){ucP.x, ucP.y}, uc23 = (f32x2){ucP.z, ucP.w};
  f32x2 mhn01 = (f32x2){mhn.x, mhn.y}, mhn23 = (f32x2){mhn.z, mhn.w};

  // ---- Pass D: column denominators; i over this wave's 32 rows ----
  float d0 = 0.f, d1 = 0.f, d2 = 0.f, d3 = 0.f;
  {
    const float* gp = G2 + i0 * NT + c4;
    const char* sb = (const char*)(sArr + i0);
#pragma unroll 2
    for (int o = 0; o < 8; ++o) {
#pragma unroll
      for (int uu = 0; uu < 4; ++uu) {
        f32x4 gP = *(const f32x4*)(gp + uu * NT);
        f32x2 su = *(const f32x2*)(sb + uu * 8);  // (r_i, u_i) broadcast
        f32x2 g01 = (f32x2){gP.x, gP.y}, g23 = (f32x2){gP.z, gP.w};
        f32x2 t01 = pk_fma_chi(wb01, g01, su);   // wb*g + u
        f32x2 t23 = pk_fma_chi(wb23, g23, su);
        f32x2 p01 = pk_fma_alo(su, t01, mhn01);  // r_i*t - mh
        f32x2 p23 = pk_fma_alo(su, t23, mhn23);
        d0 += EXP2F(p01.x); d1 += EXP2F(p01.y);
        d2 += EXP2F(p23.x); d3 += EXP2F(p23.y);
      }
      gp += 4 * NT;
      sb += 32;
    }
  }
  RRB[0][q][cq] = (f32x4){d0, d1, d2, d3};
  __syncthreads();

  // ---- reduce D -> nL per column (waves 0-3; col t = tid) ----
  if (tid < NT) {
    const float* rb = (const float*)RRB;  // [8][256] floats
    float den = rb[tid];
#pragma unroll
    for (int k = 1; k < 8; ++k) den += rb[k * 256 + tid];
    float nl = ((const float*)MHN4)[tid] - LOG2F(den);
    ((float*)(WL + tid))[1] = nl;
  }
  __syncthreads();

  // ---- Pass S: row sums of normalized att; rows c4..c4+3, j over 32 ----
  float S0 = 0.f, S1 = 0.f, S2 = 0.f, S3 = 0.f;
  {
    const float* gp = G2 + i0 * NT + c4;  // G[c][j]=G[j][c] by symmetry
    const char* wb_ = (const char*)(WL + i0);
#pragma unroll 2
    for (int o = 0; o < 8; ++o) {
#pragma unroll
      for (int uu = 0; uu < 4; ++uu) {
        f32x4 gP = *(const f32x4*)(gp + uu * NT);
        f32x2 wl = *(const f32x2*)(wb_ + uu * 8);  // (w_j, nL_j) broadcast
        f32x2 g01 = (f32x2){gP.x, gP.y}, g23 = (f32x2){gP.z, gP.w};
        f32x2 t01 = pk_fma_alo(wl, g01, uc01);  // w_j*g + uc
        f32x2 t23 = pk_fma_alo(wl, g23, uc23);
        f32x2 p01 = pk_fma_chi(rc01, t01, wl);  // rc*t - L_j
        f32x2 p23 = pk_fma_chi(rc23, t23, wl);
        S0 += EXP2F(p01.x); S1 += EXP2F(p01.y);
        S2 += EXP2F(p23.x); S3 += EXP2F(p23.y);
      }
      gp += 4 * NT;
      wb_ += 32;
    }
  }
  RRB[0][q][cq] = (f32x4){S0, S1, S2, S3};
  __syncthreads();

  // ---- reduce S -> QB = (r_t, r_t * Srow_t) ----
  if (tid < NT) {
    const float* rb = (const float*)RRB;
    float Sr = rb[tid];
#pragma unroll
    for (int k = 1; k < 8; ++k) Sr += rb[k * 256 + tid];
    f32x2 ru = sArr[tid];
    QB[tid] = (f32x2){ru.x, ru.x * Sr};
  }
  __syncthreads();

  // ---- Pass B: ave_req = (r/T)@M + bf, ave_wsdl = (Q/T)@M + bf ----
  f32x2 a01 = (f32x2){0.f, 0.f}, a23 = a01, y01 = a01, y23 = a01;
  {
    const float* mp = Mrow + i0 * NT + c4;
    const char* qb_ = (const char*)(QB + i0);
#pragma unroll 2
    for (int o = 0; o < 8; ++o) {
#pragma unroll
      for (int uu = 0; uu < 4; ++uu) {
        f32x4 mkP = *(const f32x4*)(mp + uu * NT);
        f32x2 qb = *(const f32x2*)(qb_ + uu * 8);  // (r_t, Q_t) broadcast
        f32x2 mk01 = (f32x2){mkP.x, mkP.y}, mk23 = (f32x2){mkP.z, mkP.w};
        a01 = pk_fma_alo(qb, mk01, a01);  // r_t*mk
        a23 = pk_fma_alo(qb, mk23, a23);
        y01 = pk_fma_ahi(qb, mk01, y01);  // Q_t*mk
        y23 = pk_fma_ahi(qb, mk23, y23);
      }
      mp += 4 * NT;
      qb_ += 32;
    }
  }
  RRB[0][q][cq] = (f32x4){a01.x, a01.y, a23.x, a23.y};
  RRB[1][q][cq] = (f32x4){y01.x, y01.y, y23.x, y23.y};
  __syncthreads();

  // ---- final stats (waves 0-3; col t = tid) ----
  if (tid < NT) {
    const float* rb = (const float*)RRB;
    float A = rb[tid], Y = rb[2048 + tid];
#pragma unroll
    for (int k = 1; k < 8; ++k) {
      A += rb[k * 256 + tid];
      Y += rb[2048 + k * 256 + tid];
    }
    float bfc = bf[tid];
    const float invT = 1.0f / NT;
    float avr = fmaf(A, invT, bfc);
    float avw = fmaf(Y, invT, bfc);
    float sn = avr * avw, sa = avr * avr, sc = avw * avw;
#pragma unroll
    for (int off = 32; off > 0; off >>= 1) {
      sn += __shfl_down(sn, off, 64);
      sa += __shfl_down(sa, off, 64);
      sc += __shfl_down(sc, off, 64);
    }
    if ((tid & 63) == 0) {
      int w = tid >> 6;
      fin[w][0] = sn;
      fin[w][1] = sa;
      fin[w][2] = sc;
    }
  }
  __syncthreads();
  if (tid == 0) {
    float N = fin[0][0] + fin[1][0] + fin[2][0] + fin[3][0];
    float A = fin[0][1] + fin[1][1] + fin[2][1] + fin[3][1];
    float C = fin[0][2] + fin[1][2] + fin[2][2] + fin[3][2];
    out[b] = N / fmaxf(sqrtf(A) * sqrtf(C), 1e-8f) * 3.0f;
  }
}

extern "C" void kernel_launch(void* const* d_in, const int* in_sizes, int n_in,
                              void* d_out, int out_size, void* d_ws, size_t ws_size,
                              hipStream_t stream) {
  const float* req  = (const float*)d_in[0];
  const float* wsdl = (const float*)d_in[1];
  const float* TE   = (const float*)d_in[2];
  const float* wf   = (const float*)d_in[3];
  const float* bf   = (const float*)d_in[4];
  float* out = (float*)d_out;

  // ws: [Mt | Mrow | G2 | u2 | Gd | Gof]
  float* Mt   = (float*)d_ws;
  float* Mrow = Mt + NT * NT;
  float* G2   = Mrow + NT * NT;
  float* u2   = G2 + NT * NT;
  float* Gd   = u2 + NT;
  float* Gof  = Gd + NT;

  k_M<<<NT, 1024, 0, stream>>>(TE, wf, Mt, Mrow);
  k_G<<<NT, 1024, 0, stream>>>(Mt, Mrow, bf, G2, u2, Gd, Gof);
  k_main<<<NB, 512, 0, stream>>>(req, wsdl, Mrow, G2, u2, Gd, Gof, bf, out);
}

// Round 5
// 94.872 us; speedup vs baseline: 2.6076x; 1.0825x over previous
//
#include <hip/hip_runtime.h>
#include <math.h>

constexpr int NB = 1024;   // batch
constexpr int NT = 256;    // topic_size
constexpr int NE = 300;    // embedding_size
constexpr int NBATCH = 2;  // batches per k_main block

typedef float f32x2 __attribute__((ext_vector_type(2)));
typedef float f32x4 __attribute__((ext_vector_type(4)));

#if defined(__has_builtin)
#if __has_builtin(__builtin_amdgcn_exp2f)
#define EXP2F(x) __builtin_amdgcn_exp2f(x)
#else
#define EXP2F(x) exp2f(x)
#endif
#if __has_builtin(__builtin_amdgcn_logf)
#define LOG2F(x) __builtin_amdgcn_logf(x)
#else
#define LOG2F(x) log2f(x)
#endif
#else
#define EXP2F(x) exp2f(x)
#define LOG2F(x) log2f(x)
#endif

__device__ __forceinline__ float rdlane(float v, int l) {
  return __uint_as_float(__builtin_amdgcn_readlane(__float_as_uint(v), l));
}

// ===== packed f32 FMA helpers (VOP3P); all variants HW-proven (R2/R4,
// absmax 0.0).  op_sel[i]: half of src i feeding LOW result; op_sel_hi[i]:
// half feeding HIGH result.
__device__ __forceinline__ f32x2 pk_fma(f32x2 a, f32x2 b, f32x2 c) {
  f32x2 d;
  asm("v_pk_fma_f32 %0, %1, %2, %3" : "=v"(d) : "v"(a), "v"(b), "v"(c));
  return d;
}
__device__ __forceinline__ f32x2 pk_fma_alo(f32x2 a, f32x2 b, f32x2 c) {
  f32x2 d;
  asm("v_pk_fma_f32 %0, %1, %2, %3 op_sel:[0,0,0] op_sel_hi:[0,1,1]"
      : "=v"(d) : "v"(a), "v"(b), "v"(c));
  return d;
}
__device__ __forceinline__ f32x2 pk_fma_ahi(f32x2 a, f32x2 b, f32x2 c) {
  f32x2 d;
  asm("v_pk_fma_f32 %0, %1, %2, %3 op_sel:[1,0,0] op_sel_hi:[1,1,1]"
      : "=v"(d) : "v"(a), "v"(b), "v"(c));
  return d;
}
__device__ __forceinline__ f32x2 pk_fma_clo(f32x2 a, f32x2 b, f32x2 c) {
  f32x2 d;
  asm("v_pk_fma_f32 %0, %1, %2, %3 op_sel:[0,0,0] op_sel_hi:[1,1,0]"
      : "=v"(d) : "v"(a), "v"(b), "v"(c));
  return d;
}
__device__ __forceinline__ f32x2 pk_fma_chi(f32x2 a, f32x2 b, f32x2 c) {
  f32x2 d;
  asm("v_pk_fma_f32 %0, %1, %2, %3 op_sel:[0,0,1] op_sel_hi:[1,1,1]"
      : "=v"(d) : "v"(a), "v"(b), "v"(c));
  return d;
}

// ===== k_M: column blk of M. Mt[blk][t]=sum_e TE[e,t]*wf[blk,e].  (proven)
__global__ __launch_bounds__(1024) void k_M(const float* __restrict__ TE,
                                            const float* __restrict__ wf,
                                            float* __restrict__ Mt,
                                            float* __restrict__ Mrow) {
  __shared__ float red[4][NT];
  int tid = threadIdx.x;
  int q = __builtin_amdgcn_readfirstlane(tid >> 8);
  int c = tid & 255, lane = tid & 63, blk = blockIdx.x;

  const float* wrow = wf + blk * NE;
  float4 wa = *(const float4*)(wrow + 4 * lane);
  float4 wb = make_float4(0.f, 0.f, 0.f, 0.f);
  if (lane < 11) wb = *(const float4*)(wrow + 256 + 4 * lane);
  float acc = 0.f;
#pragma unroll
  for (int k = 0; k < 16; ++k) {  // chunks q+4k <= 63
    int ec = q + 4 * k;
    float wx = rdlane(wa.x, ec), wy = rdlane(wa.y, ec);
    float wz = rdlane(wa.z, ec), ww = rdlane(wa.w, ec);
    const float* tp = TE + 4 * ec * NT + c;
    acc = fmaf(tp[0], wx, acc);
    acc = fmaf(tp[NT], wy, acc);
    acc = fmaf(tp[2 * NT], wz, acc);
    acc = fmaf(tp[3 * NT], ww, acc);
  }
#pragma unroll
  for (int k = 16; k < 19; ++k) {  // chunks 64..74
    int ec = q + 4 * k;
    if (ec < 75) {  // wave-uniform
      int l = ec - 64;
      float wx = rdlane(wb.x, l), wy = rdlane(wb.y, l);
      float wz = rdlane(wb.z, l), ww = rdlane(wb.w, l);
      const float* tp = TE + 4 * ec * NT + c;
      acc = fmaf(tp[0], wx, acc);
      acc = fmaf(tp[NT], wy, acc);
      acc = fmaf(tp[2 * NT], wz, acc);
      acc = fmaf(tp[3 * NT], ww, acc);
    }
  }
  red[q][c] = acc;
  __syncthreads();
  if (q == 0) {
    float s = red[0][c] + red[1][c] + red[2][c] + red[3][c];
    Mt[blk * NT + c] = s;    // coalesced
    Mrow[c * NT + blk] = s;  // scattered, one-time
  }
}

// ===== k_G: row blk of G2=(M M^T)*log2e; Gd, Gof, u2.  (proven)
__global__ __launch_bounds__(1024) void k_G(const float* __restrict__ Mt,
                                            const float* __restrict__ Mrow,
                                            const float* __restrict__ bf,
                                            float* __restrict__ G2,
                                            float* __restrict__ u2,
                                            float* __restrict__ Gd,
                                            float* __restrict__ Gof) {
  __shared__ float red[4][NT];
  __shared__ float fin2[4][2];
  const float LOG2E = 1.4426950408889634f;
  int tid = threadIdx.x;
  int q = __builtin_amdgcn_readfirstlane(tid >> 8);
  int c = tid & 255, lane = tid & 63, wid = tid >> 6, blk = blockIdx.x;

  const float* mrowp = Mrow + blk * NT;
  float4 ma = *(const float4*)(mrowp + 4 * lane);
  float acc = 0.f;
  int c0 = q * 16;
#pragma unroll
  for (int k = 0; k < 16; ++k) {
    int fc = c0 + k;  // SGPR
    float mx = rdlane(ma.x, fc), my = rdlane(ma.y, fc);
    float mz = rdlane(ma.z, fc), mw = rdlane(ma.w, fc);
    const float* tp = Mt + 4 * fc * NT + c;
    acc = fmaf(tp[0], mx, acc);
    acc = fmaf(tp[NT], my, acc);
    acc = fmaf(tp[2 * NT], mz, acc);
    acc = fmaf(tp[3 * NT], mw, acc);
  }
  red[q][c] = acc;
  __syncthreads();
  if (q == 0) {
    float g = (red[0][c] + red[1][c] + red[2][c] + red[3][c]) * LOG2E;
    G2[blk * NT + c] = g;
    if (c == blk) Gd[blk] = g;
    float v = (c == blk) ? -3.0e38f : g;
#pragma unroll
    for (int off = 32; off > 0; off >>= 1) v = fmaxf(v, __shfl_down(v, off, 64));
    if (lane == 0) fin2[wid][0] = v;
    float p = mrowp[c] * bf[c];  // coalesced
#pragma unroll
    for (int off = 32; off > 0; off >>= 1) p += __shfl_down(p, off, 64);
    if (lane == 0) fin2[wid][1] = p;
  }
  __syncthreads();
  if (tid == 0) {
    float gof = fmaxf(fmaxf(fin2[0][0], fin2[1][0]), fmaxf(fin2[2][0], fin2[3][0]));
    Gof[blk] = fmaxf(gof, 0.f);
    u2[blk] = (fin2[0][1] + fin2[1][1] + fin2[2][1] + fin2[3][1]) * LOG2E;
  }
}

// ===== k_main: 512 threads (8 waves), NBATCH=2, grid 512.
// Combines R4's small barrier domains with R2's per-batch amortization:
// one G2/Mrow dwordx4 + one ds_read_b128 broadcast now feed BOTH batches
// (8 exps), halving per-batch vmem/ds instr counts, L2 traffic, and
// barrier/serial-section cost.  Inner fma pairings + reduction trees keep
// the R2/R4-proven orders (absmax 0.0 expected).
__global__ __launch_bounds__(512, 4) void k_main(
    const float* __restrict__ req, const float* __restrict__ wsdl,
    const float* __restrict__ Mrow, const float* __restrict__ G2,
    const float* __restrict__ u2, const float* __restrict__ Gd,
    const float* __restrict__ Gof, const float* __restrict__ bf,
    float* __restrict__ out) {
  __shared__ f32x4 sArr[NT];       // (r0_i, r1_i, u_i, u_i)          4 KB
  __shared__ f32x4 WL[NT];         // (w0_j, w1_j, nL0_j, nL1_j)      4 KB
  __shared__ f32x4 QB[NT];         // (r0_t, r1_t, Q0_t, Q1_t)        4 KB
  __shared__ f32x4 MHN[2][64];     // -mh per batch per column        2 KB
  __shared__ f32x4 RRB[4][8][64];  // 8-way cross-wave partials      32 KB
  __shared__ float finU[4];
  __shared__ float fin[4][6];

  int tid = threadIdx.x;
  int cq = tid & 63, q = tid >> 6;  // q == wave id; wave-uniform
  int c4 = cq * 4;
  int blk = blockIdx.x, b0 = blk * NBATCH, i0 = q * 32;

  // ---- stage loop-scalar arrays + up partials (waves 0-3) ----
  if (tid < NT) {
    float r0 = req[b0 * NT + tid], r1 = req[(b0 + 1) * NT + tid];
    float u = u2[tid];
    sArr[tid] = (f32x4){r0, r1, u, u};
    WL[tid] = (f32x4){wsdl[b0 * NT + tid], wsdl[(b0 + 1) * NT + tid], 0.f, 0.f};
    float um = fmaxf(u, 0.f);
#pragma unroll
    for (int off = 32; off > 0; off >>= 1) um = fmaxf(um, __shfl_down(um, off, 64));
    if ((tid & 63) == 0) finU[tid >> 6] = um;
  }

  // ---- per-thread column-quad constants (dwordx4) ----
  f32x4 rc0P = *(const f32x4*)(req + b0 * NT + c4);
  f32x4 rc1P = *(const f32x4*)(req + (b0 + 1) * NT + c4);
  f32x4 wb0P = *(const f32x4*)(wsdl + b0 * NT + c4);
  f32x4 wb1P = *(const f32x4*)(wsdl + (b0 + 1) * NT + c4);
  f32x4 ucP = *(const f32x4*)(u2 + c4);
  f32x4 gdP = *(const f32x4*)(Gd + c4);
  f32x4 gofP = *(const f32x4*)(Gof + c4);

  __syncthreads();  // staging + finU ready
  float up = fmaxf(fmaxf(finU[0], finU[1]), fmaxf(finU[2], finU[3]));

  // Safe softmax upper bound per (batch, column) — proven formula.
  f32x4 mhn0, mhn1;
  mhn0.x = -fmaxf(rc0P.x * fmaf(wb0P.x, gdP.x, ucP.x), fmaf(wb0P.x, gofP.x, up));
  mhn0.y = -fmaxf(rc0P.y * fmaf(wb0P.y, gdP.y, ucP.y), fmaf(wb0P.y, gofP.y, up));
  mhn0.z = -fmaxf(rc0P.z * fmaf(wb0P.z, gdP.z, ucP.z), fmaf(wb0P.z, gofP.z, up));
  mhn0.w = -fmaxf(rc0P.w * fmaf(wb0P.w, gdP.w, ucP.w), fmaf(wb0P.w, gofP.w, up));
  mhn1.x = -fmaxf(rc1P.x * fmaf(wb1P.x, gdP.x, ucP.x), fmaf(wb1P.x, gofP.x, up));
  mhn1.y = -fmaxf(rc1P.y * fmaf(wb1P.y, gdP.y, ucP.y), fmaf(wb1P.y, gofP.y, up));
  mhn1.z = -fmaxf(rc1P.z * fmaf(wb1P.z, gdP.z, ucP.z), fmaf(wb1P.z, gofP.z, up));
  mhn1.w = -fmaxf(rc1P.w * fmaf(wb1P.w, gdP.w, ucP.w), fmaf(wb1P.w, gofP.w, up));
  if (q == 0) {  // covered by post-D barrier
    MHN[0][cq] = mhn0;
    MHN[1][cq] = mhn1;
  }

  f32x2 wb0_01 = (f32x2){wb0P.x, wb0P.y}, wb0_23 = (f32x2){wb0P.z, wb0P.w};
  f32x2 wb1_01 = (f32x2){wb1P.x, wb1P.y}, wb1_23 = (f32x2){wb1P.z, wb1P.w};
  f32x2 rc0_01 = (f32x2){rc0P.x, rc0P.y}, rc0_23 = (f32x2){rc0P.z, rc0P.w};
  f32x2 rc1_01 = (f32x2){rc1P.x, rc1P.y}, rc1_23 = (f32x2){rc1P.z, rc1P.w};
  f32x2 uc01 = (f32x2){ucP.x, ucP.y}, uc23 = (f32x2){ucP.z, ucP.w};
  f32x2 mhn0_01 = (f32x2){mhn0.x, mhn0.y}, mhn0_23 = (f32x2){mhn0.z, mhn0.w};
  f32x2 mhn1_01 = (f32x2){mhn1.x, mhn1.y}, mhn1_23 = (f32x2){mhn1.z, mhn1.w};

  // ---- Pass D: column denominators, both batches; i over wave's 32 rows ----
  float d00 = 0.f, d01 = 0.f, d02 = 0.f, d03 = 0.f;
  float d10 = 0.f, d11 = 0.f, d12 = 0.f, d13 = 0.f;
  {
    const float* gp = G2 + i0 * NT + c4;
    const char* sb = (const char*)(sArr + i0);
#pragma unroll 2
    for (int o = 0; o < 8; ++o) {
#pragma unroll
      for (int uu = 0; uu < 4; ++uu) {
        f32x4 gP = *(const f32x4*)(gp + uu * NT);
        f32x4 su = *(const f32x4*)(sb + uu * 16);  // (r0,r1,u,u) broadcast
        f32x2 su_lo = (f32x2){su.x, su.y};         // (r0, r1)
        f32x2 uu_ = (f32x2){su.z, su.w};           // (u, u)
        f32x2 g01 = (f32x2){gP.x, gP.y}, g23 = (f32x2){gP.z, gP.w};
        f32x2 t0_01 = pk_fma(wb0_01, g01, uu_);    // wb0*g + u
        f32x2 t0_23 = pk_fma(wb0_23, g23, uu_);
        f32x2 t1_01 = pk_fma(wb1_01, g01, uu_);
        f32x2 t1_23 = pk_fma(wb1_23, g23, uu_);
        f32x2 p0_01 = pk_fma_alo(su_lo, t0_01, mhn0_01);  // r0*t - mh0
        f32x2 p0_23 = pk_fma_alo(su_lo, t0_23, mhn0_23);
        f32x2 p1_01 = pk_fma_ahi(su_lo, t1_01, mhn1_01);  // r1*t - mh1
        f32x2 p1_23 = pk_fma_ahi(su_lo, t1_23, mhn1_23);
        d00 += EXP2F(p0_01.x); d01 += EXP2F(p0_01.y);
        d02 += EXP2F(p0_23.x); d03 += EXP2F(p0_23.y);
        d10 += EXP2F(p1_01.x); d11 += EXP2F(p1_01.y);
        d12 += EXP2F(p1_23.x); d13 += EXP2F(p1_23.y);
      }
      gp += 4 * NT;
      sb += 64;
    }
  }
  RRB[0][q][cq] = (f32x4){d00, d01, d02, d03};
  RRB[1][q][cq] = (f32x4){d10, d11, d12, d13};
  __syncthreads();

  // ---- reduce D -> nL per (batch, column) (waves 0-3; col t = tid) ----
  if (tid < NT) {
    const float* rb = (const float*)RRB;  // flat: b*2048 + q*256 + col
    float den0 = rb[tid], den1 = rb[2048 + tid];
#pragma unroll
    for (int k = 1; k < 8; ++k) {
      den0 += rb[k * 256 + tid];
      den1 += rb[2048 + k * 256 + tid];
    }
    float nl0 = ((const float*)MHN)[tid] - LOG2F(den0);
    float nl1 = ((const float*)MHN)[256 + tid] - LOG2F(den1);
    ((float*)(WL + tid))[2] = nl0;
    ((float*)(WL + tid))[3] = nl1;
  }
  __syncthreads();

  // ---- Pass S: row sums of normalized att; rows c4..c4+3, both batches ----
  float S00 = 0.f, S01 = 0.f, S02 = 0.f, S03 = 0.f;
  float S10 = 0.f, S11 = 0.f, S12 = 0.f, S13 = 0.f;
  {
    const float* gp = G2 + i0 * NT + c4;  // G[c][j]=G[j][c] by symmetry
    const char* wb_ = (const char*)(WL + i0);
#pragma unroll 2
    for (int o = 0; o < 8; ++o) {
#pragma unroll
      for (int uu = 0; uu < 4; ++uu) {
        f32x4 gP = *(const f32x4*)(gp + uu * NT);
        f32x4 wl = *(const f32x4*)(wb_ + uu * 16);  // (w0,w1,nL0,nL1)
        f32x2 wl_lo = (f32x2){wl.x, wl.y};
        f32x2 wl_hi = (f32x2){wl.z, wl.w};
        f32x2 g01 = (f32x2){gP.x, gP.y}, g23 = (f32x2){gP.z, gP.w};
        f32x2 t0_01 = pk_fma_alo(wl_lo, g01, uc01);  // w0_j*g + uc
        f32x2 t0_23 = pk_fma_alo(wl_lo, g23, uc23);
        f32x2 t1_01 = pk_fma_ahi(wl_lo, g01, uc01);  // w1_j*g + uc
        f32x2 t1_23 = pk_fma_ahi(wl_lo, g23, uc23);
        f32x2 p0_01 = pk_fma_clo(rc0_01, t0_01, wl_hi);  // rc0*t - L0_j
        f32x2 p0_23 = pk_fma_clo(rc0_23, t0_23, wl_hi);
        f32x2 p1_01 = pk_fma_chi(rc1_01, t1_01, wl_hi);  // rc1*t - L1_j
        f32x2 p1_23 = pk_fma_chi(rc1_23, t1_23, wl_hi);
        S00 += EXP2F(p0_01.x); S01 += EXP2F(p0_01.y);
        S02 += EXP2F(p0_23.x); S03 += EXP2F(p0_23.y);
        S10 += EXP2F(p1_01.x); S11 += EXP2F(p1_01.y);
        S12 += EXP2F(p1_23.x); S13 += EXP2F(p1_23.y);
      }
      gp += 4 * NT;
      wb_ += 64;
    }
  }
  RRB[0][q][cq] = (f32x4){S00, S01, S02, S03};
  RRB[1][q][cq] = (f32x4){S10, S11, S12, S13};
  __syncthreads();

  // ---- reduce S -> QB = (r0, r1, r0*Srow0, r1*Srow1) ----
  if (tid < NT) {
    const float* rb = (const float*)RRB;
    float Sr0 = rb[tid], Sr1 = rb[2048 + tid];
#pragma unroll
    for (int k = 1; k < 8; ++k) {
      Sr0 += rb[k * 256 + tid];
      Sr1 += rb[2048 + k * 256 + tid];
    }
    f32x4 ru = sArr[tid];
    QB[tid] = (f32x4){ru.x, ru.y, ru.x * Sr0, ru.y * Sr1};
  }
  __syncthreads();

  // ---- Pass B: ave_req = (r/T)@M + bf, ave_wsdl = (Q/T)@M + bf ----
  f32x2 a0_01 = (f32x2){0.f, 0.f}, a0_23 = a0_01, a1_01 = a0_01, a1_23 = a0_01;
  f32x2 y0_01 = a0_01, y0_23 = a0_01, y1_01 = a0_01, y1_23 = a0_01;
  {
    const float* mp = Mrow + i0 * NT + c4;
    const char* qb_ = (const char*)(QB + i0);
#pragma unroll 2
    for (int o = 0; o < 8; ++o) {
#pragma unroll
      for (int uu = 0; uu < 4; ++uu) {
        f32x4 mkP = *(const f32x4*)(mp + uu * NT);
        f32x4 qb = *(const f32x4*)(qb_ + uu * 16);  // (r0,r1,Q0,Q1)
        f32x2 qb_lo = (f32x2){qb.x, qb.y};
        f32x2 qb_hi = (f32x2){qb.z, qb.w};
        f32x2 mk01 = (f32x2){mkP.x, mkP.y}, mk23 = (f32x2){mkP.z, mkP.w};
        a0_01 = pk_fma_alo(qb_lo, mk01, a0_01);  // r0_t*mk
        a0_23 = pk_fma_alo(qb_lo, mk23, a0_23);
        a1_01 = pk_fma_ahi(qb_lo, mk01, a1_01);  // r1_t*mk
        a1_23 = pk_fma_ahi(qb_lo, mk23, a1_23);
        y0_01 = pk_fma_alo(qb_hi, mk01, y0_01);  // Q0_t*mk
        y0_23 = pk_fma_alo(qb_hi, mk23, y0_23);
        y1_01 = pk_fma_ahi(qb_hi, mk01, y1_01);  // Q1_t*mk
        y1_23 = pk_fma_ahi(qb_hi, mk23, y1_23);
      }
      mp += 4 * NT;
      qb_ += 64;
    }
  }
  RRB[0][q][cq] = (f32x4){a0_01.x, a0_01.y, a0_23.x, a0_23.y};
  RRB[1][q][cq] = (f32x4){a1_01.x, a1_01.y, a1_23.x, a1_23.y};
  RRB[2][q][cq] = (f32x4){y0_01.x, y0_01.y, y0_23.x, y0_23.y};
  RRB[3][q][cq] = (f32x4){y1_01.x, y1_01.y, y1_23.x, y1_23.y};
  __syncthreads();

  // ---- final stats (waves 0-3; col t = tid) ----
  if (tid < NT) {
    const float* rb = (const float*)RRB;
    float A0 = rb[tid], A1 = rb[2048 + tid];
    float Y0 = rb[4096 + tid], Y1 = rb[6144 + tid];
#pragma unroll
    for (int k = 1; k < 8; ++k) {
      A0 += rb[k * 256 + tid];
      A1 += rb[2048 + k * 256 + tid];
      Y0 += rb[4096 + k * 256 + tid];
      Y1 += rb[6144 + k * 256 + tid];
    }
    float bfc = bf[tid];
    const float invT = 1.0f / NT;
    float avr0 = fmaf(A0, invT, bfc);
    float avr1 = fmaf(A1, invT, bfc);
    float avw0 = fmaf(Y0, invT, bfc);
    float avw1 = fmaf(Y1, invT, bfc);
    float st[6];
    st[0] = avr0 * avw0; st[1] = avr0 * avr0; st[2] = avw0 * avw0;
    st[3] = avr1 * avw1; st[4] = avr1 * avr1; st[5] = avw1 * avw1;
#pragma unroll
    for (int k = 0; k < 6; ++k)
#pragma unroll
      for (int off = 32; off > 0; off >>= 1) st[k] += __shfl_down(st[k], off, 64);
    if ((tid & 63) == 0) {
      int w = tid >> 6;
#pragma unroll
      for (int k = 0; k < 6; ++k) fin[w][k] = st[k];
    }
  }
  __syncthreads();
  if (tid < NBATCH) {
    int bb = tid;
    float N = 0.f, A = 0.f, C = 0.f;
#pragma unroll
    for (int w = 0; w < 4; ++w) {
      N += fin[w][3 * bb + 0];
      A += fin[w][3 * bb + 1];
      C += fin[w][3 * bb + 2];
    }
    out[b0 + bb] = N / fmaxf(sqrtf(A) * sqrtf(C), 1e-8f) * 3.0f;
  }
}

extern "C" void kernel_launch(void* const* d_in, const int* in_sizes, int n_in,
                              void* d_out, int out_size, void* d_ws, size_t ws_size,
                              hipStream_t stream) {
  const float* req  = (const float*)d_in[0];
  const float* wsdl = (const float*)d_in[1];
  const float* TE   = (const float*)d_in[2];
  const float* wf   = (const float*)d_in[3];
  const float* bf   = (const float*)d_in[4];
  float* out = (float*)d_out;

  // ws: [Mt | Mrow | G2 | u2 | Gd | Gof]
  float* Mt   = (float*)d_ws;
  float* Mrow = Mt + NT * NT;
  float* G2   = Mrow + NT * NT;
  float* u2   = G2 + NT * NT;
  float* Gd   = u2 + NT;
  float* Gof  = Gd + NT;

  k_M<<<NT, 1024, 0, stream>>>(TE, wf, Mt, Mrow);
  k_G<<<NT, 1024, 0, stream>>>(Mt, Mrow, bf, G2, u2, Gd, Gof);
  k_main<<<NB / NBATCH, 512, 0, stream>>>(req, wsdl, Mrow, G2, u2, Gd, Gof,
                                          bf, out);
}

// Round 6
// 94.253 us; speedup vs baseline: 2.6248x; 1.0066x over previous
//
#include <hip/hip_runtime.h>
#include <math.h>

constexpr int NB = 1024;   // batch
constexpr int NT = 256;    // topic_size
constexpr int NE = 300;    // embedding_size
constexpr int NBATCH = 2;  // batches per k_main block

typedef float f32x2 __attribute__((ext_vector_type(2)));
typedef float f32x4 __attribute__((ext_vector_type(4)));

#if defined(__has_builtin)
#if __has_builtin(__builtin_amdgcn_exp2f)
#define EXP2F(x) __builtin_amdgcn_exp2f(x)
#else
#define EXP2F(x) exp2f(x)
#endif
#if __has_builtin(__builtin_amdgcn_logf)
#define LOG2F(x) __builtin_amdgcn_logf(x)
#else
#define LOG2F(x) log2f(x)
#endif
#else
#define EXP2F(x) exp2f(x)
#define LOG2F(x) log2f(x)
#endif

__device__ __forceinline__ float rdlane(float v, int l) {
  return __uint_as_float(__builtin_amdgcn_readlane(__float_as_uint(v), l));
}

// ===== packed f32 FMA helpers (VOP3P); all variants HW-proven (R2/R4/R5,
// absmax 0.0).  op_sel[i]: half of src i feeding LOW result; op_sel_hi[i]:
// half feeding HIGH result.
__device__ __forceinline__ f32x2 pk_fma(f32x2 a, f32x2 b, f32x2 c) {
  f32x2 d;
  asm("v_pk_fma_f32 %0, %1, %2, %3" : "=v"(d) : "v"(a), "v"(b), "v"(c));
  return d;
}
__device__ __forceinline__ f32x2 pk_fma_alo(f32x2 a, f32x2 b, f32x2 c) {
  f32x2 d;
  asm("v_pk_fma_f32 %0, %1, %2, %3 op_sel:[0,0,0] op_sel_hi:[0,1,1]"
      : "=v"(d) : "v"(a), "v"(b), "v"(c));
  return d;
}
__device__ __forceinline__ f32x2 pk_fma_ahi(f32x2 a, f32x2 b, f32x2 c) {
  f32x2 d;
  asm("v_pk_fma_f32 %0, %1, %2, %3 op_sel:[1,0,0] op_sel_hi:[1,1,1]"
      : "=v"(d) : "v"(a), "v"(b), "v"(c));
  return d;
}
__device__ __forceinline__ f32x2 pk_fma_clo(f32x2 a, f32x2 b, f32x2 c) {
  f32x2 d;
  asm("v_pk_fma_f32 %0, %1, %2, %3 op_sel:[0,0,0] op_sel_hi:[1,1,0]"
      : "=v"(d) : "v"(a), "v"(b), "v"(c));
  return d;
}
__device__ __forceinline__ f32x2 pk_fma_chi(f32x2 a, f32x2 b, f32x2 c) {
  f32x2 d;
  asm("v_pk_fma_f32 %0, %1, %2, %3 op_sel:[0,0,1] op_sel_hi:[1,1,1]"
      : "=v"(d) : "v"(a), "v"(b), "v"(c));
  return d;
}

// ===== k_M: column blk of M. Mt[blk][t]=sum_e TE[e,t]*wf[blk,e].  (proven)
__global__ __launch_bounds__(1024) void k_M(const float* __restrict__ TE,
                                            const float* __restrict__ wf,
                                            float* __restrict__ Mt,
                                            float* __restrict__ Mrow) {
  __shared__ float red[4][NT];
  int tid = threadIdx.x;
  int q = __builtin_amdgcn_readfirstlane(tid >> 8);
  int c = tid & 255, lane = tid & 63, blk = blockIdx.x;

  const float* wrow = wf + blk * NE;
  float4 wa = *(const float4*)(wrow + 4 * lane);
  float4 wb = make_float4(0.f, 0.f, 0.f, 0.f);
  if (lane < 11) wb = *(const float4*)(wrow + 256 + 4 * lane);
  float acc = 0.f;
#pragma unroll
  for (int k = 0; k < 16; ++k) {  // chunks q+4k <= 63
    int ec = q + 4 * k;
    float wx = rdlane(wa.x, ec), wy = rdlane(wa.y, ec);
    float wz = rdlane(wa.z, ec), ww = rdlane(wa.w, ec);
    const float* tp = TE + 4 * ec * NT + c;
    acc = fmaf(tp[0], wx, acc);
    acc = fmaf(tp[NT], wy, acc);
    acc = fmaf(tp[2 * NT], wz, acc);
    acc = fmaf(tp[3 * NT], ww, acc);
  }
#pragma unroll
  for (int k = 16; k < 19; ++k) {  // chunks 64..74
    int ec = q + 4 * k;
    if (ec < 75) {  // wave-uniform
      int l = ec - 64;
      float wx = rdlane(wb.x, l), wy = rdlane(wb.y, l);
      float wz = rdlane(wb.z, l), ww = rdlane(wb.w, l);
      const float* tp = TE + 4 * ec * NT + c;
      acc = fmaf(tp[0], wx, acc);
      acc = fmaf(tp[NT], wy, acc);
      acc = fmaf(tp[2 * NT], wz, acc);
      acc = fmaf(tp[3 * NT], ww, acc);
    }
  }
  red[q][c] = acc;
  __syncthreads();
  if (q == 0) {
    float s = red[0][c] + red[1][c] + red[2][c] + red[3][c];
    Mt[blk * NT + c] = s;    // coalesced
    Mrow[c * NT + blk] = s;  // scattered, one-time
  }
}

// ===== k_G: row blk of G2=(M M^T)*log2e; Gd, Gof, u2.  (proven)
__global__ __launch_bounds__(1024) void k_G(const float* __restrict__ Mt,
                                            const float* __restrict__ Mrow,
                                            const float* __restrict__ bf,
                                            float* __restrict__ G2,
                                            float* __restrict__ u2,
                                            float* __restrict__ Gd,
                                            float* __restrict__ Gof) {
  __shared__ float red[4][NT];
  __shared__ float fin2[4][2];
  const float LOG2E = 1.4426950408889634f;
  int tid = threadIdx.x;
  int q = __builtin_amdgcn_readfirstlane(tid >> 8);
  int c = tid & 255, lane = tid & 63, wid = tid >> 6, blk = blockIdx.x;

  const float* mrowp = Mrow + blk * NT;
  float4 ma = *(const float4*)(mrowp + 4 * lane);
  float acc = 0.f;
  int c0 = q * 16;
#pragma unroll
  for (int k = 0; k < 16; ++k) {
    int fc = c0 + k;  // SGPR
    float mx = rdlane(ma.x, fc), my = rdlane(ma.y, fc);
    float mz = rdlane(ma.z, fc), mw = rdlane(ma.w, fc);
    const float* tp = Mt + 4 * fc * NT + c;
    acc = fmaf(tp[0], mx, acc);
    acc = fmaf(tp[NT], my, acc);
    acc = fmaf(tp[2 * NT], mz, acc);
    acc = fmaf(tp[3 * NT], mw, acc);
  }
  red[q][c] = acc;
  __syncthreads();
  if (q == 0) {
    float g = (red[0][c] + red[1][c] + red[2][c] + red[3][c]) * LOG2E;
    G2[blk * NT + c] = g;
    if (c == blk) Gd[blk] = g;
    float v = (c == blk) ? -3.0e38f : g;
#pragma unroll
    for (int off = 32; off > 0; off >>= 1) v = fmaxf(v, __shfl_down(v, off, 64));
    if (lane == 0) fin2[wid][0] = v;
    float p = mrowp[c] * bf[c];  // coalesced
#pragma unroll
    for (int off = 32; off > 0; off >>= 1) p += __shfl_down(p, off, 64);
    if (lane == 0) fin2[wid][1] = p;
  }
  __syncthreads();
  if (tid == 0) {
    float gof = fmaxf(fmaxf(fin2[0][0], fin2[1][0]), fmaxf(fin2[2][0], fin2[3][0]));
    Gof[blk] = fmaxf(gof, 0.f);
    u2[blk] = (fin2[0][1] + fin2[1][1] + fin2[2][1] + fin2[3][1]) * LOG2E;
  }
}

// ===== k_main: R5 structure (512 thr, NBATCH=2, grid 512) +
//  (1) serial reduce sections batch-split across ALL 8 waves (bsel=tid>>8),
//  (2) f32x2 packed accumulation of exp results (v_pk_add_f32),
//  (3) QB (r0,r1) halves staged in preamble.
// All reduction trees keep the R5-proven per-batch shapes -> bit-identical.
__global__ __launch_bounds__(512, 4) void k_main(
    const float* __restrict__ req, const float* __restrict__ wsdl,
    const float* __restrict__ Mrow, const float* __restrict__ G2,
    const float* __restrict__ u2, const float* __restrict__ Gd,
    const float* __restrict__ Gof, const float* __restrict__ bf,
    float* __restrict__ out) {
  __shared__ f32x4 sArr[NT];       // (r0_i, r1_i, u_i, u_i)          4 KB
  __shared__ f32x4 WL[NT];         // (w0_j, w1_j, nL0_j, nL1_j)      4 KB
  __shared__ f32x4 QB[NT];         // (r0_t, r1_t, Q0_t, Q1_t)        4 KB
  __shared__ f32x4 MHN[2][64];     // -mh per batch per column        2 KB
  __shared__ f32x4 RRB[4][8][64];  // 8-way cross-wave partials      32 KB
  __shared__ float finU[4];
  __shared__ float fin[8][3];

  int tid = threadIdx.x;
  int cq = tid & 63, q = tid >> 6;  // q == wave id; wave-uniform
  int c4 = cq * 4;
  int blk = blockIdx.x, b0 = blk * NBATCH, i0 = q * 32;

  // ---- stage loop-scalar arrays + up partials (waves 0-3) ----
  if (tid < NT) {
    float r0 = req[b0 * NT + tid], r1 = req[(b0 + 1) * NT + tid];
    float u = u2[tid];
    sArr[tid] = (f32x4){r0, r1, u, u};
    WL[tid] = (f32x4){wsdl[b0 * NT + tid], wsdl[(b0 + 1) * NT + tid], 0.f, 0.f};
    QB[tid] = (f32x4){r0, r1, 0.f, 0.f};
    float um = fmaxf(u, 0.f);
#pragma unroll
    for (int off = 32; off > 0; off >>= 1) um = fmaxf(um, __shfl_down(um, off, 64));
    if ((tid & 63) == 0) finU[tid >> 6] = um;
  }

  // ---- per-thread column-quad constants (dwordx4) ----
  f32x4 rc0P = *(const f32x4*)(req + b0 * NT + c4);
  f32x4 rc1P = *(const f32x4*)(req + (b0 + 1) * NT + c4);
  f32x4 wb0P = *(const f32x4*)(wsdl + b0 * NT + c4);
  f32x4 wb1P = *(const f32x4*)(wsdl + (b0 + 1) * NT + c4);
  f32x4 ucP = *(const f32x4*)(u2 + c4);
  f32x4 gdP = *(const f32x4*)(Gd + c4);
  f32x4 gofP = *(const f32x4*)(Gof + c4);

  __syncthreads();  // staging + finU ready
  float up = fmaxf(fmaxf(finU[0], finU[1]), fmaxf(finU[2], finU[3]));

  // Safe softmax upper bound per (batch, column) — proven formula.
  f32x4 mhn0, mhn1;
  mhn0.x = -fmaxf(rc0P.x * fmaf(wb0P.x, gdP.x, ucP.x), fmaf(wb0P.x, gofP.x, up));
  mhn0.y = -fmaxf(rc0P.y * fmaf(wb0P.y, gdP.y, ucP.y), fmaf(wb0P.y, gofP.y, up));
  mhn0.z = -fmaxf(rc0P.z * fmaf(wb0P.z, gdP.z, ucP.z), fmaf(wb0P.z, gofP.z, up));
  mhn0.w = -fmaxf(rc0P.w * fmaf(wb0P.w, gdP.w, ucP.w), fmaf(wb0P.w, gofP.w, up));
  mhn1.x = -fmaxf(rc1P.x * fmaf(wb1P.x, gdP.x, ucP.x), fmaf(wb1P.x, gofP.x, up));
  mhn1.y = -fmaxf(rc1P.y * fmaf(wb1P.y, gdP.y, ucP.y), fmaf(wb1P.y, gofP.y, up));
  mhn1.z = -fmaxf(rc1P.z * fmaf(wb1P.z, gdP.z, ucP.z), fmaf(wb1P.z, gofP.z, up));
  mhn1.w = -fmaxf(rc1P.w * fmaf(wb1P.w, gdP.w, ucP.w), fmaf(wb1P.w, gofP.w, up));
  if (q == 0) {  // covered by post-D barrier
    MHN[0][cq] = mhn0;
    MHN[1][cq] = mhn1;
  }

  f32x2 wb0_01 = (f32x2){wb0P.x, wb0P.y}, wb0_23 = (f32x2){wb0P.z, wb0P.w};
  f32x2 wb1_01 = (f32x2){wb1P.x, wb1P.y}, wb1_23 = (f32x2){wb1P.z, wb1P.w};
  f32x2 rc0_01 = (f32x2){rc0P.x, rc0P.y}, rc0_23 = (f32x2){rc0P.z, rc0P.w};
  f32x2 rc1_01 = (f32x2){rc1P.x, rc1P.y}, rc1_23 = (f32x2){rc1P.z, rc1P.w};
  f32x2 uc01 = (f32x2){ucP.x, ucP.y}, uc23 = (f32x2){ucP.z, ucP.w};
  f32x2 mhn0_01 = (f32x2){mhn0.x, mhn0.y}, mhn0_23 = (f32x2){mhn0.z, mhn0.w};
  f32x2 mhn1_01 = (f32x2){mhn1.x, mhn1.y}, mhn1_23 = (f32x2){mhn1.z, mhn1.w};

  // ---- Pass D: column denominators, both batches; i over wave's 32 rows ----
  f32x2 d0a = (f32x2){0.f, 0.f}, d0b = d0a, d1a = d0a, d1b = d0a;
  {
    const float* gp = G2 + i0 * NT + c4;
    const char* sb = (const char*)(sArr + i0);
#pragma unroll 2
    for (int o = 0; o < 8; ++o) {
#pragma unroll
      for (int uu = 0; uu < 4; ++uu) {
        f32x4 gP = *(const f32x4*)(gp + uu * NT);
        f32x4 su = *(const f32x4*)(sb + uu * 16);  // (r0,r1,u,u) broadcast
        f32x2 su_lo = (f32x2){su.x, su.y};         // (r0, r1)
        f32x2 uu_ = (f32x2){su.z, su.w};           // (u, u)
        f32x2 g01 = (f32x2){gP.x, gP.y}, g23 = (f32x2){gP.z, gP.w};
        f32x2 t0_01 = pk_fma(wb0_01, g01, uu_);    // wb0*g + u
        f32x2 t0_23 = pk_fma(wb0_23, g23, uu_);
        f32x2 t1_01 = pk_fma(wb1_01, g01, uu_);
        f32x2 t1_23 = pk_fma(wb1_23, g23, uu_);
        f32x2 p0_01 = pk_fma_alo(su_lo, t0_01, mhn0_01);  // r0*t - mh0
        f32x2 p0_23 = pk_fma_alo(su_lo, t0_23, mhn0_23);
        f32x2 p1_01 = pk_fma_ahi(su_lo, t1_01, mhn1_01);  // r1*t - mh1
        f32x2 p1_23 = pk_fma_ahi(su_lo, t1_23, mhn1_23);
        d0a += (f32x2){EXP2F(p0_01.x), EXP2F(p0_01.y)};
        d0b += (f32x2){EXP2F(p0_23.x), EXP2F(p0_23.y)};
        d1a += (f32x2){EXP2F(p1_01.x), EXP2F(p1_01.y)};
        d1b += (f32x2){EXP2F(p1_23.x), EXP2F(p1_23.y)};
      }
      gp += 4 * NT;
      sb += 64;
    }
  }
  RRB[0][q][cq] = (f32x4){d0a.x, d0a.y, d0b.x, d0b.y};
  RRB[1][q][cq] = (f32x4){d1a.x, d1a.y, d1b.x, d1b.y};
  __syncthreads();

  // ---- reduce D -> nL, batch-split over ALL 8 waves (bit-identical) ----
  {
    int bsel = tid >> 8, col = tid & 255;
    const float* rb = (const float*)RRB + bsel * 2048;
    float den = rb[col];
#pragma unroll
    for (int k = 1; k < 8; ++k) den += rb[k * 256 + col];
    float nl = ((const float*)MHN)[tid] - LOG2F(den);
    ((float*)(WL + col))[2 + bsel] = nl;
  }
  __syncthreads();

  // ---- Pass S: row sums of normalized att; rows c4..c4+3, both batches ----
  f32x2 S0a = (f32x2){0.f, 0.f}, S0b = S0a, S1a = S0a, S1b = S0a;
  {
    const float* gp = G2 + i0 * NT + c4;  // G[c][j]=G[j][c] by symmetry
    const char* wb_ = (const char*)(WL + i0);
#pragma unroll 2
    for (int o = 0; o < 8; ++o) {
#pragma unroll
      for (int uu = 0; uu < 4; ++uu) {
        f32x4 gP = *(const f32x4*)(gp + uu * NT);
        f32x4 wl = *(const f32x4*)(wb_ + uu * 16);  // (w0,w1,nL0,nL1)
        f32x2 wl_lo = (f32x2){wl.x, wl.y};
        f32x2 wl_hi = (f32x2){wl.z, wl.w};
        f32x2 g01 = (f32x2){gP.x, gP.y}, g23 = (f32x2){gP.z, gP.w};
        f32x2 t0_01 = pk_fma_alo(wl_lo, g01, uc01);  // w0_j*g + uc
        f32x2 t0_23 = pk_fma_alo(wl_lo, g23, uc23);
        f32x2 t1_01 = pk_fma_ahi(wl_lo, g01, uc01);  // w1_j*g + uc
        f32x2 t1_23 = pk_fma_ahi(wl_lo, g23, uc23);
        f32x2 p0_01 = pk_fma_clo(rc0_01, t0_01, wl_hi);  // rc0*t - L0_j
        f32x2 p0_23 = pk_fma_clo(rc0_23, t0_23, wl_hi);
        f32x2 p1_01 = pk_fma_chi(rc1_01, t1_01, wl_hi);  // rc1*t - L1_j
        f32x2 p1_23 = pk_fma_chi(rc1_23, t1_23, wl_hi);
        S0a += (f32x2){EXP2F(p0_01.x), EXP2F(p0_01.y)};
        S0b += (f32x2){EXP2F(p0_23.x), EXP2F(p0_23.y)};
        S1a += (f32x2){EXP2F(p1_01.x), EXP2F(p1_01.y)};
        S1b += (f32x2){EXP2F(p1_23.x), EXP2F(p1_23.y)};
      }
      gp += 4 * NT;
      wb_ += 64;
    }
  }
  RRB[0][q][cq] = (f32x4){S0a.x, S0a.y, S0b.x, S0b.y};
  RRB[1][q][cq] = (f32x4){S1a.x, S1a.y, S1b.x, S1b.y};
  __syncthreads();

  // ---- reduce S -> QB z/w, batch-split over ALL 8 waves ----
  {
    int bsel = tid >> 8, col = tid & 255;
    const float* rb = (const float*)RRB + bsel * 2048;
    float Sr = rb[col];
#pragma unroll
    for (int k = 1; k < 8; ++k) Sr += rb[k * 256 + col];
    float r = ((const float*)(sArr + col))[bsel];
    ((float*)(QB + col))[2 + bsel] = r * Sr;
  }
  __syncthreads();

  // ---- Pass B: ave_req = (r/T)@M + bf, ave_wsdl = (Q/T)@M + bf ----
  f32x2 a0_01 = (f32x2){0.f, 0.f}, a0_23 = a0_01, a1_01 = a0_01, a1_23 = a0_01;
  f32x2 y0_01 = a0_01, y0_23 = a0_01, y1_01 = a0_01, y1_23 = a0_01;
  {
    const float* mp = Mrow + i0 * NT + c4;
    const char* qb_ = (const char*)(QB + i0);
#pragma unroll 2
    for (int o = 0; o < 8; ++o) {
#pragma unroll
      for (int uu = 0; uu < 4; ++uu) {
        f32x4 mkP = *(const f32x4*)(mp + uu * NT);
        f32x4 qb = *(const f32x4*)(qb_ + uu * 16);  // (r0,r1,Q0,Q1)
        f32x2 qb_lo = (f32x2){qb.x, qb.y};
        f32x2 qb_hi = (f32x2){qb.z, qb.w};
        f32x2 mk01 = (f32x2){mkP.x, mkP.y}, mk23 = (f32x2){mkP.z, mkP.w};
        a0_01 = pk_fma_alo(qb_lo, mk01, a0_01);  // r0_t*mk
        a0_23 = pk_fma_alo(qb_lo, mk23, a0_23);
        a1_01 = pk_fma_ahi(qb_lo, mk01, a1_01);  // r1_t*mk
        a1_23 = pk_fma_ahi(qb_lo, mk23, a1_23);
        y0_01 = pk_fma_alo(qb_hi, mk01, y0_01);  // Q0_t*mk
        y0_23 = pk_fma_alo(qb_hi, mk23, y0_23);
        y1_01 = pk_fma_ahi(qb_hi, mk01, y1_01);  // Q1_t*mk
        y1_23 = pk_fma_ahi(qb_hi, mk23, y1_23);
      }
      mp += 4 * NT;
      qb_ += 64;
    }
  }
  RRB[0][q][cq] = (f32x4){a0_01.x, a0_01.y, a0_23.x, a0_23.y};
  RRB[1][q][cq] = (f32x4){a1_01.x, a1_01.y, a1_23.x, a1_23.y};
  RRB[2][q][cq] = (f32x4){y0_01.x, y0_01.y, y0_23.x, y0_23.y};
  RRB[3][q][cq] = (f32x4){y1_01.x, y1_01.y, y1_23.x, y1_23.y};
  __syncthreads();

  // ---- final stats, batch-split over ALL 8 waves (3 reduces/thread) ----
  {
    int bsel = tid >> 8, col = tid & 255;
    const float* rb = (const float*)RRB + bsel * 2048;
    float A = rb[col], Y = rb[4096 + col];  // a at 0/2048; y at 4096/6144
#pragma unroll
    for (int k = 1; k < 8; ++k) {
      A += rb[k * 256 + col];
      Y += rb[4096 + k * 256 + col];
    }
    float bfc = bf[col];
    const float invT = 1.0f / NT;
    float avr = fmaf(A, invT, bfc);
    float avw = fmaf(Y, invT, bfc);
    float sn = avr * avw, sa = avr * avr, sc = avw * avw;
#pragma unroll
    for (int off = 32; off > 0; off >>= 1) {
      sn += __shfl_down(sn, off, 64);
      sa += __shfl_down(sa, off, 64);
      sc += __shfl_down(sc, off, 64);
    }
    if ((tid & 63) == 0) {
      int w = tid >> 6;  // 0-3: batch0, 4-7: batch1
      fin[w][0] = sn;
      fin[w][1] = sa;
      fin[w][2] = sc;
    }
  }
  __syncthreads();
  if (tid < NBATCH) {
    int bb = tid;
    float N = 0.f, A = 0.f, C = 0.f;
#pragma unroll
    for (int w = 0; w < 4; ++w) {
      N += fin[bb * 4 + w][0];
      A += fin[bb * 4 + w][1];
      C += fin[bb * 4 + w][2];
    }
    out[b0 + bb] = N / fmaxf(sqrtf(A) * sqrtf(C), 1e-8f) * 3.0f;
  }
}

extern "C" void kernel_launch(void* const* d_in, const int* in_sizes, int n_in,
                              void* d_out, int out_size, void* d_ws, size_t ws_size,
                              hipStream_t stream) {
  const float* req  = (const float*)d_in[0];
  const float* wsdl = (const float*)d_in[1];
  const float* TE   = (const float*)d_in[2];
  const float* wf   = (const float*)d_in[3];
  const float* bf   = (const float*)d_in[4];
  float* out = (float*)d_out;

  // ws: [Mt | Mrow | G2 | u2 | Gd | Gof]
  float* Mt   = (float*)d_ws;
  float* Mrow = Mt + NT * NT;
  float* G2   = Mrow + NT * NT;
  float* u2   = G2 + NT * NT;
  float* Gd   = u2 + NT;
  float* Gof  = Gd + NT;

  k_M<<<NT, 1024, 0, stream>>>(TE, wf, Mt, Mrow);
  k_G<<<NT, 1024, 0, stream>>>(Mt, Mrow, bf, G2, u2, Gd, Gof);
  k_main<<<NB / NBATCH, 512, 0, stream>>>(req, wsdl, Mrow, G2, u2, Gd, Gof,
                                          bf, out);
}